// Round 1
// baseline (455.561 us; speedup 1.0000x reference)
//
#include <hip/hip_runtime.h>
#include <stdint.h>

// Problem constants (B=4, S=2048, H=1024, E=8, M=512, K=2, SM=1024, G=64)
#define T_TOK 8192
#define H_DIM 1024
#define M_DIM 512
#define SM_DIM 1024
#define E_NUM 8
#define S_SEQ 2048
#define G_DIM 64
#define NASSIGN 16384                      // T_TOK * 2
#define NSLOT (NASSIGN + E_NUM * 128)      // compact slots + per-expert tile padding
#define MAX_TILES (NASSIGN / 128 + E_NUM)  // 136

typedef float f32x4 __attribute__((ext_vector_type(4)));
typedef short bf16x8 __attribute__((ext_vector_type(8)));

struct TileDesc { int base; int expert; int nrows; };

static __device__ __forceinline__ ushort f2b(float f) {
  union { float f; uint32_t u; } a; a.f = f;
  uint32_t r = a.u + 0x7fffu + ((a.u >> 16) & 1u);  // RNE
  return (ushort)(r >> 16);
}
static __device__ __forceinline__ float b2f(ushort u) {
  union { uint32_t u; float f; } a; a.u = ((uint32_t)u) << 16;
  return a.f;
}

// ---------------- conversion kernels ----------------
__global__ void cvt_x_kernel(const float* __restrict__ x, ushort* __restrict__ xb) {
  int i = blockIdx.x * 256 + threadIdx.x;  // T_TOK*H_DIM/4 threads
  const float4 v = ((const float4*)x)[i];
  ushort4 o;
  o.x = f2b(v.x); o.y = f2b(v.y); o.z = f2b(v.z); o.w = f2b(v.w);
  ((ushort4*)xb)[i] = o;
}

// src: batch of (R x C) f32 row-major -> dst: (C x R) bf16 row-major (transpose+convert)
__global__ void tcvt_kernel(const float* __restrict__ src, ushort* __restrict__ dst, int R, int C) {
  __shared__ float tile[32][33];
  size_t bo = (size_t)blockIdx.z * R * C;
  src += bo; dst += bo;
  int c0 = blockIdx.x * 32, r0 = blockIdx.y * 32;
#pragma unroll
  for (int i = 0; i < 4; ++i)
    tile[threadIdx.y + i * 8][threadIdx.x] =
        src[(size_t)(r0 + threadIdx.y + i * 8) * C + c0 + threadIdx.x];
  __syncthreads();
#pragma unroll
  for (int i = 0; i < 4; ++i)
    dst[(size_t)(c0 + threadIdx.y + i * 8) * R + r0 + threadIdx.x] =
        f2b(tile[threadIdx.x][threadIdx.y + i * 8]);
}

// ---------------- routing ----------------
// logits_g[b][e] = g[b] . wg[e]; also zero the expert counters.
__global__ void lg_kernel(const float* __restrict__ g, const float* __restrict__ wg,
                          float* __restrict__ lg, int* __restrict__ counts) {
  int tid = threadIdx.x;
  if (tid < E_NUM) counts[tid] = 0;
  if (tid < 4 * E_NUM) {
    int b = tid >> 3, e = tid & 7;
    float s = 0.f;
    for (int i = 0; i < G_DIM; ++i) s += g[b * G_DIM + i] * wg[e * G_DIM + i];
    lg[tid] = s;
  }
}

// one wave per token: 8 f32 logits, top-2, normalized softmax weights
__global__ __launch_bounds__(64) void router_kernel(
    const float* __restrict__ x, const float* __restrict__ wt, const float* __restrict__ lg,
    int* __restrict__ tidx, float* __restrict__ tw) {
  int t = blockIdx.x;
  int lane = threadIdx.x;
  const float* xr = x + (size_t)t * H_DIM;
  float a[E_NUM];
#pragma unroll
  for (int e = 0; e < E_NUM; ++e) a[e] = 0.f;
  for (int i = lane; i < H_DIM; i += 64) {
    float xv = xr[i];
#pragma unroll
    for (int e = 0; e < E_NUM; ++e) a[e] += xv * wt[e * H_DIM + i];
  }
#pragma unroll
  for (int e = 0; e < E_NUM; ++e)
    for (int off = 32; off; off >>= 1) a[e] += __shfl_xor(a[e], off, 64);
  if (lane == 0) {
    int b = t / S_SEQ;
    float l[E_NUM];
#pragma unroll
    for (int e = 0; e < E_NUM; ++e) l[e] = 0.5f * (a[e] + lg[b * E_NUM + e]);
    int i1 = 0; float b1 = l[0];
#pragma unroll
    for (int e = 1; e < E_NUM; ++e) if (l[e] > b1) { b1 = l[e]; i1 = e; }
    int i2 = -1; float b2 = -1e30f;
#pragma unroll
    for (int e = 0; e < E_NUM; ++e) if (e != i1 && l[e] > b2) { b2 = l[e]; i2 = e; }
    float e2 = expf(b2 - b1);            // e1 = 1
    float inv = 1.f / (1.f + e2);
    tidx[t * 2] = i1; tidx[t * 2 + 1] = i2;
    tw[t * 2] = inv;  tw[t * 2 + 1] = e2 * inv;
  }
}

__global__ void count_kernel(const int* __restrict__ tidx, int* __restrict__ counts) {
  int i = blockIdx.x * 256 + threadIdx.x;
  if (i < NASSIGN) atomicAdd(&counts[tidx[i]], 1);
}

__global__ void scan_desc_kernel(const int* __restrict__ counts, int* __restrict__ offs,
                                 TileDesc* __restrict__ desc, int* __restrict__ ndesc) {
  if (threadIdx.x != 0) return;
  int o = 0, nd = 0;
  for (int e = 0; e < E_NUM; ++e) {
    offs[e] = o;
    int n = counts[e];
    for (int tb = 0; tb < n; tb += 128) {
      desc[nd].base = o + tb; desc[nd].expert = e;
      desc[nd].nrows = (n - tb < 128) ? (n - tb) : 128;
      ++nd;
    }
    o += n;
  }
  offs[E_NUM] = o;
  *ndesc = nd;
}

// stable (deterministic) compaction: one wave, ballot/popcount ranking
__global__ __launch_bounds__(64) void place_kernel(
    const int* __restrict__ tidx, const int* __restrict__ offs,
    int* __restrict__ perm, int* __restrict__ slot_of) {
  int lane = threadIdx.x;
  int base[E_NUM];
#pragma unroll
  for (int e = 0; e < E_NUM; ++e) base[e] = offs[e];
  unsigned long long lower = (lane == 63) ? 0x7fffffffffffffffull : ((1ull << lane) - 1ull);
  for (int it = 0; it < NASSIGN; it += 64) {
    int i = it + lane;
    int e = tidx[i];
    int pos = 0;
#pragma unroll
    for (int ee = 0; ee < E_NUM; ++ee) {
      unsigned long long m = __ballot(e == ee);
      if (e == ee) pos = base[ee] + __popcll(m & lower);
      base[ee] += __popcll(m);
    }
    perm[pos] = i >> 1;
    slot_of[i] = pos;
  }
}

// ---------------- GEMM kernels (16x16x32 bf16 MFMA) ----------------
// Dual GEMM: out = leaky(A@B0t^T) * (A@B1t^T), bf16 out.  Tiles: BM=128, BN=64, BK=32.
// A: (rows x Kd) bf16 row-major. B0t/B1t: (Nd x Kd) bf16 row-major (pre-transposed), per-expert stride Nd*Kd.
__global__ __launch_bounds__(256) void gemm_dual_kernel(
    const ushort* __restrict__ A, const ushort* __restrict__ B0t, const ushort* __restrict__ B1t,
    ushort* __restrict__ Hout, int Kd, int Nd,
    const int* __restrict__ perm, const TileDesc* __restrict__ desc, const int* __restrict__ ndesc) {
  __shared__ ushort As[128][40];
  __shared__ ushort B0s[64][40];
  __shared__ ushort B1s[64][40];

  int rowbase, nrows;
  const ushort *b0g, *b1g;
  if (desc) {
    if (blockIdx.x >= (unsigned)*ndesc) return;
    TileDesc d = desc[blockIdx.x];
    rowbase = d.base; nrows = d.nrows;
    size_t wo = (size_t)d.expert * Nd * Kd;
    b0g = B0t + wo; b1g = B1t + wo;
  } else {
    rowbase = blockIdx.x * 128; nrows = 128; b0g = B0t; b1g = B1t;
  }
  int n0 = blockIdx.y * 64;
  int tid = threadIdx.x;

  // A staging: thread -> (row, 16-elem half)
  int ar = tid >> 1, ah = (tid & 1) * 16;
  int arr = (ar < nrows) ? ar : 0;
  int arow = desc ? perm[rowbase + arr] : (rowbase + ar);
  const ushort* aptr = A + (size_t)arow * Kd + ah;
  // B staging: thread -> (n, 8-elem quarter)
  int bn = tid >> 2, bk = (tid & 3) * 8;
  const ushort* b0ptr = b0g + (size_t)(n0 + bn) * Kd + bk;
  const ushort* b1ptr = b1g + (size_t)(n0 + bn) * Kd + bk;

  int wv = tid >> 6, lane = tid & 63;
  int wr = wv >> 1, wc = wv & 1;
  int lr = lane & 15, lk = (lane >> 4) * 8;

  f32x4 acc0[4][2], acc1[4][2];
#pragma unroll
  for (int m = 0; m < 4; ++m)
#pragma unroll
    for (int n = 0; n < 2; ++n) { acc0[m][n] = (f32x4){0.f,0.f,0.f,0.f}; acc1[m][n] = (f32x4){0.f,0.f,0.f,0.f}; }

  int nk = Kd >> 5;
  for (int kt = 0; kt < nk; ++kt) {
    __syncthreads();
    {
      uint4 v0 = *(const uint4*)(aptr);
      uint4 v1 = *(const uint4*)(aptr + 8);
      *(uint4*)&As[ar][ah] = v0;
      *(uint4*)&As[ar][ah + 8] = v1;
      uint4 w0 = *(const uint4*)(b0ptr);
      *(uint4*)&B0s[bn][bk] = w0;
      uint4 w1 = *(const uint4*)(b1ptr);
      *(uint4*)&B1s[bn][bk] = w1;
    }
    aptr += 32; b0ptr += 32; b1ptr += 32;
    __syncthreads();
    bf16x8 af[4], bf0[2], bf1[2];
#pragma unroll
    for (int m = 0; m < 4; ++m) af[m] = *(const bf16x8*)&As[wr * 64 + m * 16 + lr][lk];
#pragma unroll
    for (int n = 0; n < 2; ++n) {
      bf0[n] = *(const bf16x8*)&B0s[wc * 32 + n * 16 + lr][lk];
      bf1[n] = *(const bf16x8*)&B1s[wc * 32 + n * 16 + lr][lk];
    }
#pragma unroll
    for (int m = 0; m < 4; ++m)
#pragma unroll
      for (int n = 0; n < 2; ++n) {
        acc0[m][n] = __builtin_amdgcn_mfma_f32_16x16x32_bf16(af[m], bf0[n], acc0[m][n], 0, 0, 0);
        acc1[m][n] = __builtin_amdgcn_mfma_f32_16x16x32_bf16(af[m], bf1[n], acc1[m][n], 0, 0, 0);
      }
  }
  // epilogue: h = leaky(g)*u  (C/D layout: col=lane&15, row=(lane>>4)*4+reg)
  int rq = (lane >> 4) * 4, cq = lane & 15;
#pragma unroll
  for (int m = 0; m < 4; ++m)
#pragma unroll
    for (int n = 0; n < 2; ++n)
#pragma unroll
      for (int r = 0; r < 4; ++r) {
        int row = wr * 64 + m * 16 + rq + r;
        if (row < nrows) {
          float gv = acc0[m][n][r], uv = acc1[m][n][r];
          float hv = (gv >= 0.f ? gv : 0.01f * gv) * uv;
          int col = n0 + wc * 32 + n * 16 + cq;
          Hout[(size_t)(rowbase + row) * Nd + col] = f2b(hv);
        }
      }
}

// Single GEMM: out = A@Bt^T.  Tiles: BM=128, BN=128, BK=32. BF16OUT: 0 -> f32 out, 1 -> bf16 out.
template <int BF16OUT>
__global__ __launch_bounds__(256) void gemm_single_kernel(
    const ushort* __restrict__ A, const ushort* __restrict__ Bt, void* __restrict__ Out,
    int Kd, int Nd, const TileDesc* __restrict__ desc, const int* __restrict__ ndesc) {
  __shared__ ushort As[128][40];
  __shared__ ushort Bs[128][40];

  int rowbase, nrows;
  const ushort* bg;
  if (desc) {
    if (blockIdx.x >= (unsigned)*ndesc) return;
    TileDesc d = desc[blockIdx.x];
    rowbase = d.base; nrows = d.nrows;
    bg = Bt + (size_t)d.expert * Nd * Kd;
  } else {
    rowbase = blockIdx.x * 128; nrows = 128; bg = Bt;
  }
  int n0 = blockIdx.y * 128;
  int tid = threadIdx.x;

  int ar = tid >> 1, ah = (tid & 1) * 16;
  int arr = (ar < nrows) ? ar : 0;
  const ushort* aptr = A + (size_t)(rowbase + arr) * Kd + ah;  // A rows are slots/tokens directly
  const ushort* bptr = bg + (size_t)(n0 + ar) * Kd + ah;

  int wv = tid >> 6, lane = tid & 63;
  int wr = wv >> 1, wc = wv & 1;
  int lr = lane & 15, lk = (lane >> 4) * 8;

  f32x4 acc[4][4];
#pragma unroll
  for (int m = 0; m < 4; ++m)
#pragma unroll
    for (int n = 0; n < 4; ++n) acc[m][n] = (f32x4){0.f,0.f,0.f,0.f};

  int nk = Kd >> 5;
  for (int kt = 0; kt < nk; ++kt) {
    __syncthreads();
    {
      uint4 v0 = *(const uint4*)(aptr);
      uint4 v1 = *(const uint4*)(aptr + 8);
      *(uint4*)&As[ar][ah] = v0;
      *(uint4*)&As[ar][ah + 8] = v1;
      uint4 w0 = *(const uint4*)(bptr);
      uint4 w1 = *(const uint4*)(bptr + 8);
      *(uint4*)&Bs[ar][ah] = w0;
      *(uint4*)&Bs[ar][ah + 8] = w1;
    }
    aptr += 32; bptr += 32;
    __syncthreads();
    bf16x8 af[4], bfr[4];
#pragma unroll
    for (int m = 0; m < 4; ++m) af[m] = *(const bf16x8*)&As[wr * 64 + m * 16 + lr][lk];
#pragma unroll
    for (int n = 0; n < 4; ++n) bfr[n] = *(const bf16x8*)&Bs[wc * 64 + n * 16 + lr][lk];
#pragma unroll
    for (int m = 0; m < 4; ++m)
#pragma unroll
      for (int n = 0; n < 4; ++n)
        acc[m][n] = __builtin_amdgcn_mfma_f32_16x16x32_bf16(af[m], bfr[n], acc[m][n], 0, 0, 0);
  }
  int rq = (lane >> 4) * 4, cq = lane & 15;
#pragma unroll
  for (int m = 0; m < 4; ++m)
#pragma unroll
    for (int n = 0; n < 4; ++n)
#pragma unroll
      for (int r = 0; r < 4; ++r) {
        int row = wr * 64 + m * 16 + rq + r;
        if (row < nrows) {
          int col = n0 + wc * 64 + n * 16 + cq;
          size_t o = (size_t)(rowbase + row) * Nd + col;
          if (BF16OUT) ((ushort*)Out)[o] = f2b(acc[m][n][r]);
          else ((float*)Out)[o] = acc[m][n][r];
        }
      }
}

// y[t] += w0*ye[s0] + w1*ye[s1]   (y already holds shared-expert p)
__global__ void final_kernel(float* __restrict__ y, const ushort* __restrict__ ye,
                             const int* __restrict__ slot_of, const float* __restrict__ tw) {
  int i = blockIdx.x * 256 + threadIdx.x;  // T_TOK*H_DIM/4 threads
  int t = i >> 8;
  int c4 = (i & 255) * 4;
  int s0 = slot_of[t * 2], s1 = slot_of[t * 2 + 1];
  float w0 = tw[t * 2], w1 = tw[t * 2 + 1];
  float4 v = ((float4*)y)[i];
  ushort4 a = *(const ushort4*)(ye + (size_t)s0 * H_DIM + c4);
  ushort4 b = *(const ushort4*)(ye + (size_t)s1 * H_DIM + c4);
  v.x += w0 * b2f(a.x) + w1 * b2f(b.x);
  v.y += w0 * b2f(a.y) + w1 * b2f(b.y);
  v.z += w0 * b2f(a.z) + w1 * b2f(b.z);
  v.w += w0 * b2f(a.w) + w1 * b2f(b.w);
  ((float4*)y)[i] = v;
}

// ---------------- host ----------------
extern "C" void kernel_launch(void* const* d_in, const int* in_sizes, int n_in,
                              void* d_out, int out_size, void* d_ws, size_t ws_size,
                              hipStream_t stream) {
  const float* x       = (const float*)d_in[0];
  const float* g       = (const float*)d_in[1];
  const float* wt      = (const float*)d_in[2];
  const float* wg      = (const float*)d_in[3];
  const float* w_gate  = (const float*)d_in[4];
  const float* w_up    = (const float*)d_in[5];
  const float* w_down  = (const float*)d_in[6];
  const float* sw_gate = (const float*)d_in[7];
  const float* sw_up   = (const float*)d_in[8];
  const float* sw_down = (const float*)d_in[9];
  float* y = (float*)d_out;

  char* p = (char*)d_ws;
  auto alloc = [&](size_t bytes) -> char* {
    char* r = p;
    p += (bytes + 255) & ~(size_t)255;
    return r;
  };
  ushort* xb    = (ushort*)alloc((size_t)T_TOK * H_DIM * 2);
  ushort* wg_t  = (ushort*)alloc((size_t)E_NUM * M_DIM * H_DIM * 2);  // (E, M, H)
  ushort* wu_t  = (ushort*)alloc((size_t)E_NUM * M_DIM * H_DIM * 2);
  ushort* wd_t  = (ushort*)alloc((size_t)E_NUM * H_DIM * M_DIM * 2);  // (E, H, M)
  ushort* swg_t = (ushort*)alloc((size_t)SM_DIM * H_DIM * 2);         // (SM, H)
  ushort* swu_t = (ushort*)alloc((size_t)SM_DIM * H_DIM * 2);
  ushort* swd_t = (ushort*)alloc((size_t)H_DIM * SM_DIM * 2);         // (H, SM)
  float* lg     = (float*)alloc(4 * E_NUM * 4);
  int* tidx     = (int*)alloc(NASSIGN * 4);
  float* tw     = (float*)alloc(NASSIGN * 4);
  int* counts   = (int*)alloc(E_NUM * 4);
  int* offs     = (int*)alloc((E_NUM + 1) * 4);
  int* ndesc    = (int*)alloc(4);
  int* perm     = (int*)alloc(NASSIGN * 4);
  int* slot_of  = (int*)alloc(NASSIGN * 4);
  TileDesc* desc = (TileDesc*)alloc(MAX_TILES * sizeof(TileDesc));
  ushort* h_e   = (ushort*)alloc((size_t)NSLOT * M_DIM * 2);
  ushort* hsh   = (ushort*)alloc((size_t)T_TOK * SM_DIM * 2);
  ushort* ye    = (ushort*)alloc((size_t)NSLOT * H_DIM * 2);
  (void)ws_size; (void)in_sizes; (void)n_in; (void)out_size;

  // conversions
  cvt_x_kernel<<<T_TOK * H_DIM / 4 / 256, 256, 0, stream>>>(x, xb);
  dim3 tb(32, 8);
  tcvt_kernel<<<dim3(M_DIM / 32, H_DIM / 32, E_NUM), tb, 0, stream>>>(w_gate, wg_t, H_DIM, M_DIM);
  tcvt_kernel<<<dim3(M_DIM / 32, H_DIM / 32, E_NUM), tb, 0, stream>>>(w_up, wu_t, H_DIM, M_DIM);
  tcvt_kernel<<<dim3(H_DIM / 32, M_DIM / 32, E_NUM), tb, 0, stream>>>(w_down, wd_t, M_DIM, H_DIM);
  tcvt_kernel<<<dim3(SM_DIM / 32, H_DIM / 32, 1), tb, 0, stream>>>(sw_gate, swg_t, H_DIM, SM_DIM);
  tcvt_kernel<<<dim3(SM_DIM / 32, H_DIM / 32, 1), tb, 0, stream>>>(sw_up, swu_t, H_DIM, SM_DIM);
  tcvt_kernel<<<dim3(H_DIM / 32, SM_DIM / 32, 1), tb, 0, stream>>>(sw_down, swd_t, SM_DIM, H_DIM);

  // routing
  lg_kernel<<<1, 32, 0, stream>>>(g, wg, lg, counts);
  router_kernel<<<T_TOK, 64, 0, stream>>>(x, wt, lg, tidx, tw);
  count_kernel<<<NASSIGN / 256, 256, 0, stream>>>(tidx, counts);
  scan_desc_kernel<<<1, 64, 0, stream>>>(counts, offs, desc, ndesc);
  place_kernel<<<1, 64, 0, stream>>>(tidx, offs, perm, slot_of);

  // shared expert: hsh = leaky(x@swg)*(x@swu); y = hsh@swd
  gemm_dual_kernel<<<dim3(T_TOK / 128, SM_DIM / 64), 256, 0, stream>>>(
      xb, swg_t, swu_t, hsh, H_DIM, SM_DIM, nullptr, nullptr, nullptr);
  gemm_single_kernel<0><<<dim3(T_TOK / 128, H_DIM / 128), 256, 0, stream>>>(
      hsh, swd_t, (void*)y, SM_DIM, H_DIM, nullptr, nullptr);

  // routed experts: h_e = leaky(Xg@wg)*(Xg@wu); ye = h_e@wd
  gemm_dual_kernel<<<dim3(MAX_TILES, M_DIM / 64), 256, 0, stream>>>(
      xb, wg_t, wu_t, h_e, H_DIM, M_DIM, perm, desc, ndesc);
  gemm_single_kernel<1><<<dim3(MAX_TILES, H_DIM / 128), 256, 0, stream>>>(
      h_e, wd_t, (void*)ye, M_DIM, H_DIM, desc, ndesc);

  // combine
  final_kernel<<<T_TOK * H_DIM / 4 / 256, 256, 0, stream>>>(y, ye, slot_of, tw);
}

// Round 2
// 263.933 us; speedup vs baseline: 1.7261x; 1.7261x over previous
//
#include <hip/hip_runtime.h>
#include <stdint.h>

// Problem constants (B=4, S=2048, H=1024, E=8, M=512, K=2, SM=1024, G=64)
#define T_TOK 8192
#define H_DIM 1024
#define M_DIM 512
#define SM_DIM 1024
#define E_NUM 8
#define S_SEQ 2048
#define G_DIM 64
#define NASSIGN 16384                      // T_TOK * 2
#define NSLOT (NASSIGN + E_NUM * 128)      // compact slots + per-expert tile padding
#define MAX_TILES (NASSIGN / 128 + E_NUM)  // 136
#define NBLK_PLACE (NASSIGN / 256)         // 64

typedef float f32x4 __attribute__((ext_vector_type(4)));
typedef short bf16x8 __attribute__((ext_vector_type(8)));

struct TileDesc { int base; int expert; int nrows; };

static __device__ __forceinline__ ushort f2b(float f) {
  union { float f; uint32_t u; } a; a.f = f;
  uint32_t r = a.u + 0x7fffu + ((a.u >> 16) & 1u);  // RNE
  return (ushort)(r >> 16);
}
static __device__ __forceinline__ float b2f(ushort u) {
  union { uint32_t u; float f; } a; a.u = ((uint32_t)u) << 16;
  return a.f;
}
static __device__ __forceinline__ int imin(int a, int b) { return a < b ? a : b; }

// async global->LDS, 16B per lane; LDS dest = wave-uniform base + lane*16
static __device__ __forceinline__ void gll16(const void* g, void* l) {
  __builtin_amdgcn_global_load_lds(
      (const __attribute__((address_space(1))) void*)g,
      (__attribute__((address_space(3))) void*)l, 16, 0, 0);
}
// bank-conflict swizzle for [*][32]-ushort LDS tiles (16B chunks, 4/row)
static __device__ __forceinline__ int swz(int row) { return (row >> 1) & 3; }

// ---------------- conversion kernels ----------------
__global__ void cvt_x_kernel(const float* __restrict__ x, ushort* __restrict__ xb) {
  int i = blockIdx.x * 256 + threadIdx.x;  // T_TOK*H_DIM/4 threads
  const float4 v = ((const float4*)x)[i];
  ushort4 o;
  o.x = f2b(v.x); o.y = f2b(v.y); o.z = f2b(v.z); o.w = f2b(v.w);
  ((ushort4*)xb)[i] = o;
}

// src: batch of (R x C) f32 row-major -> dst: (C x R) bf16 row-major (transpose+convert)
__global__ void tcvt_kernel(const float* __restrict__ src, ushort* __restrict__ dst, int R, int C) {
  __shared__ float tile[32][33];
  size_t bo = (size_t)blockIdx.z * R * C;
  src += bo; dst += bo;
  int c0 = blockIdx.x * 32, r0 = blockIdx.y * 32;
#pragma unroll
  for (int i = 0; i < 4; ++i)
    tile[threadIdx.y + i * 8][threadIdx.x] =
        src[(size_t)(r0 + threadIdx.y + i * 8) * C + c0 + threadIdx.x];
  __syncthreads();
#pragma unroll
  for (int i = 0; i < 4; ++i)
    dst[(size_t)(c0 + threadIdx.y + i * 8) * R + r0 + threadIdx.x] =
        f2b(tile[threadIdx.x][threadIdx.y + i * 8]);
}

// ---------------- routing ----------------
__global__ void lg_kernel(const float* __restrict__ g, const float* __restrict__ wg,
                          float* __restrict__ lg) {
  int tid = threadIdx.x;
  if (tid < 4 * E_NUM) {
    int b = tid >> 3, e = tid & 7;
    float s = 0.f;
    for (int i = 0; i < G_DIM; ++i) s += g[b * G_DIM + i] * wg[e * G_DIM + i];
    lg[tid] = s;
  }
}

// one wave per token: 8 f32 logits, top-2, normalized softmax weights
__global__ __launch_bounds__(64) void router_kernel(
    const float* __restrict__ x, const float* __restrict__ wt, const float* __restrict__ lg,
    int* __restrict__ tidx, float* __restrict__ tw) {
  int t = blockIdx.x;
  int lane = threadIdx.x;
  const float* xr = x + (size_t)t * H_DIM;
  float a[E_NUM];
#pragma unroll
  for (int e = 0; e < E_NUM; ++e) a[e] = 0.f;
  for (int i = lane; i < H_DIM; i += 64) {
    float xv = xr[i];
#pragma unroll
    for (int e = 0; e < E_NUM; ++e) a[e] += xv * wt[e * H_DIM + i];
  }
#pragma unroll
  for (int e = 0; e < E_NUM; ++e)
    for (int off = 32; off; off >>= 1) a[e] += __shfl_xor(a[e], off, 64);
  if (lane == 0) {
    int b = t / S_SEQ;
    float l[E_NUM];
#pragma unroll
    for (int e = 0; e < E_NUM; ++e) l[e] = 0.5f * (a[e] + lg[b * E_NUM + e]);
    int i1 = 0; float b1 = l[0];
#pragma unroll
    for (int e = 1; e < E_NUM; ++e) if (l[e] > b1) { b1 = l[e]; i1 = e; }
    int i2 = -1; float b2 = -1e30f;
#pragma unroll
    for (int e = 0; e < E_NUM; ++e) if (e != i1 && l[e] > b2) { b2 = l[e]; i2 = e; }
    float e2 = expf(b2 - b1);            // e1 = 1
    float inv = 1.f / (1.f + e2);
    tidx[t * 2] = i1; tidx[t * 2 + 1] = i2;
    tw[t * 2] = inv;  tw[t * 2 + 1] = e2 * inv;
  }
}

// per-256-chunk expert histogram
__global__ __launch_bounds__(256) void hist_kernel(const int* __restrict__ tidx,
                                                   int* __restrict__ bcount) {
  __shared__ int h[E_NUM];
  int tid = threadIdx.x;
  if (tid < E_NUM) h[tid] = 0;
  __syncthreads();
  atomicAdd(&h[tidx[blockIdx.x * 256 + tid]], 1);
  __syncthreads();
  if (tid < E_NUM) bcount[blockIdx.x * E_NUM + tid] = h[tid];
}

// one block: totals, expert offsets, tile descriptors, per-chunk global offsets
__global__ __launch_bounds__(64) void scan2_kernel(
    const int* __restrict__ bcount, int* __restrict__ boffs, int* __restrict__ offs,
    TileDesc* __restrict__ desc, int* __restrict__ ndesc) {
  __shared__ int cnt[E_NUM];
  __shared__ int off_s[E_NUM];
  int lane = threadIdx.x;
  if (lane < E_NUM) {
    int s = 0;
    for (int b = 0; b < NBLK_PLACE; ++b) s += bcount[b * E_NUM + lane];
    cnt[lane] = s;
  }
  __syncthreads();
  if (lane == 0) {
    int o = 0, nd = 0;
    for (int e = 0; e < E_NUM; ++e) {
      off_s[e] = o;
      offs[e] = o;
      int n = cnt[e];
      for (int tb = 0; tb < n; tb += 128) {
        desc[nd].base = o + tb; desc[nd].expert = e;
        desc[nd].nrows = imin(n - tb, 128);
        ++nd;
      }
      o += n;
    }
    offs[E_NUM] = o;
    *ndesc = nd;
  }
  __syncthreads();
  if (lane < E_NUM) {
    int run = off_s[lane];
    for (int b = 0; b < NBLK_PLACE; ++b) {
      boffs[b * E_NUM + lane] = run;
      run += bcount[b * E_NUM + lane];
    }
  }
}

// stable parallel compaction: ballot rank within wave + LDS wave-count scan
__global__ __launch_bounds__(256) void place2_kernel(
    const int* __restrict__ tidx, const int* __restrict__ boffs,
    int* __restrict__ perm, int* __restrict__ slot_of) {
  __shared__ int wcnt[4][E_NUM];
  int tid = threadIdx.x, wv = tid >> 6, lane = tid & 63;
  int i = blockIdx.x * 256 + tid;
  int e = tidx[i];
  unsigned long long lower = (lane == 63) ? 0x7fffffffffffffffull : ((1ull << lane) - 1ull);
  int rank = 0;
#pragma unroll
  for (int ee = 0; ee < E_NUM; ++ee) {
    unsigned long long m = __ballot(e == ee);
    if (e == ee) rank = __popcll(m & lower);
    if (lane == 0) wcnt[wv][ee] = __popcll(m);
  }
  __syncthreads();
  int off = boffs[blockIdx.x * E_NUM + e];
  for (int w = 0; w < wv; ++w) off += wcnt[w][e];
  int pos = off + rank;
  perm[pos] = i >> 1;
  slot_of[i] = pos;
}

// ---------------- GEMM kernels (m97 structure: global_load_lds + swizzled linear LDS) ----
// Dual GEMM: out = leaky(A@B0t^T) * (A@B1t^T), bf16 out.  BM=128, BN=64, BK=32.
__global__ __launch_bounds__(256) void gemm_dual_kernel(
    const ushort* __restrict__ A, const ushort* __restrict__ B0t, const ushort* __restrict__ B1t,
    ushort* __restrict__ Hout, int Kd, int Nd,
    const int* __restrict__ perm, const TileDesc* __restrict__ desc, const int* __restrict__ ndesc) {
  __shared__ ushort As[128 * 32];
  __shared__ ushort B0s[64 * 32];
  __shared__ ushort B1s[64 * 32];

  int rowbase, nrows;
  const ushort *b0g, *b1g;
  if (desc) {
    if (blockIdx.x >= (unsigned)*ndesc) return;
    TileDesc d = desc[blockIdx.x];
    rowbase = d.base; nrows = d.nrows;
    size_t wo = (size_t)d.expert * Nd * Kd;
    b0g = B0t + wo; b1g = B1t + wo;
  } else {
    rowbase = blockIdx.x * 128; nrows = 128; b0g = B0t; b1g = B1t;
  }
  int n0 = blockIdx.y * 64;
  int tid = threadIdx.x;
  int wv = tid >> 6, lane = tid & 63;

  // staging: wave wv issues A chunks {wv, wv+4}, B0 chunk wv, B1 chunk wv (1KB each)
  int l4 = lane >> 2, c = lane & 3;
  int a0 = wv * 16 + l4, a1 = a0 + 64;   // A tile rows
  int ga0 = desc ? perm[rowbase + imin(a0, nrows - 1)] : (rowbase + a0);
  int ga1 = desc ? perm[rowbase + imin(a1, nrows - 1)] : (rowbase + a1);
  const ushort* ap0 = A + (size_t)ga0 * Kd + ((c ^ swz(a0)) << 3);
  const ushort* ap1 = A + (size_t)ga1 * Kd + ((c ^ swz(a1)) << 3);
  int br = wv * 16 + l4;                 // B tile row (0..63)
  const ushort* bp0 = b0g + (size_t)(n0 + br) * Kd + ((c ^ swz(br)) << 3);
  const ushort* bp1 = b1g + (size_t)(n0 + br) * Kd + ((c ^ swz(br)) << 3);
  ushort* asd0 = As + wv * 512;
  ushort* asd1 = As + (wv + 4) * 512;
  ushort* b0d = B0s + wv * 512;
  ushort* b1d = B1s + wv * 512;

  int wr = wv >> 1, wc = wv & 1;
  int lr = lane & 15, cg = lane >> 4;

  f32x4 acc0[4][2], acc1[4][2];
#pragma unroll
  for (int m = 0; m < 4; ++m)
#pragma unroll
    for (int n = 0; n < 2; ++n) { acc0[m][n] = (f32x4){0.f,0.f,0.f,0.f}; acc1[m][n] = (f32x4){0.f,0.f,0.f,0.f}; }

  int nk = Kd >> 5;
  for (int kt = 0; kt < nk; ++kt) {
    gll16(ap0, asd0); gll16(ap1, asd1);
    gll16(bp0, b0d);  gll16(bp1, b1d);
    ap0 += 32; ap1 += 32; bp0 += 32; bp1 += 32;
    __syncthreads();  // drains vmcnt -> LDS ready
    bf16x8 af[4], bq0[2], bq1[2];
#pragma unroll
    for (int m = 0; m < 4; ++m) {
      int row = wr * 64 + m * 16 + lr;
      af[m] = *(const bf16x8*)&As[row * 32 + ((cg ^ swz(row)) << 3)];
    }
#pragma unroll
    for (int n = 0; n < 2; ++n) {
      int row = wc * 32 + n * 16 + lr;
      bq0[n] = *(const bf16x8*)&B0s[row * 32 + ((cg ^ swz(row)) << 3)];
      bq1[n] = *(const bf16x8*)&B1s[row * 32 + ((cg ^ swz(row)) << 3)];
    }
#pragma unroll
    for (int m = 0; m < 4; ++m)
#pragma unroll
      for (int n = 0; n < 2; ++n) {
        acc0[m][n] = __builtin_amdgcn_mfma_f32_16x16x32_bf16(af[m], bq0[n], acc0[m][n], 0, 0, 0);
        acc1[m][n] = __builtin_amdgcn_mfma_f32_16x16x32_bf16(af[m], bq1[n], acc1[m][n], 0, 0, 0);
      }
    __syncthreads();  // all waves done reading before next-stage overwrite
  }
  int rq = cg * 4, cq = lr;  // C/D layout: col=lane&15, row=(lane>>4)*4+reg
#pragma unroll
  for (int m = 0; m < 4; ++m)
#pragma unroll
    for (int n = 0; n < 2; ++n)
#pragma unroll
      for (int r = 0; r < 4; ++r) {
        int row = wr * 64 + m * 16 + rq + r;
        if (row < nrows) {
          float gv = acc0[m][n][r], uv = acc1[m][n][r];
          float hv = (gv >= 0.f ? gv : 0.01f * gv) * uv;
          int col = n0 + wc * 32 + n * 16 + cq;
          Hout[(size_t)(rowbase + row) * Nd + col] = f2b(hv);
        }
      }
}

// Single GEMM: out = A@Bt^T.  BM=128, BN=128, BK=32. BF16OUT: 0 -> f32, 1 -> bf16.
template <int BF16OUT>
__global__ __launch_bounds__(256) void gemm_single_kernel(
    const ushort* __restrict__ A, const ushort* __restrict__ Bt, void* __restrict__ Out,
    int Kd, int Nd, const TileDesc* __restrict__ desc, const int* __restrict__ ndesc) {
  __shared__ ushort As[128 * 32];
  __shared__ ushort Bs[128 * 32];

  int rowbase, nrows;
  const ushort* bg;
  if (desc) {
    if (blockIdx.x >= (unsigned)*ndesc) return;
    TileDesc d = desc[blockIdx.x];
    rowbase = d.base; nrows = d.nrows;
    bg = Bt + (size_t)d.expert * Nd * Kd;
  } else {
    rowbase = blockIdx.x * 128; nrows = 128; bg = Bt;
  }
  int n0 = blockIdx.y * 128;
  int tid = threadIdx.x;
  int wv = tid >> 6, lane = tid & 63;

  int l4 = lane >> 2, c = lane & 3;
  int a0 = wv * 16 + l4, a1 = a0 + 64;
  const ushort* ap0 = A + (size_t)(rowbase + a0) * Kd + ((c ^ swz(a0)) << 3);
  const ushort* ap1 = A + (size_t)(rowbase + a1) * Kd + ((c ^ swz(a1)) << 3);
  const ushort* bp0 = bg + (size_t)(n0 + a0) * Kd + ((c ^ swz(a0)) << 3);
  const ushort* bp1 = bg + (size_t)(n0 + a1) * Kd + ((c ^ swz(a1)) << 3);
  ushort* asd0 = As + wv * 512;
  ushort* asd1 = As + (wv + 4) * 512;
  ushort* bsd0 = Bs + wv * 512;
  ushort* bsd1 = Bs + (wv + 4) * 512;

  int wr = wv >> 1, wc = wv & 1;
  int lr = lane & 15, cg = lane >> 4;

  f32x4 acc[4][4];
#pragma unroll
  for (int m = 0; m < 4; ++m)
#pragma unroll
    for (int n = 0; n < 4; ++n) acc[m][n] = (f32x4){0.f,0.f,0.f,0.f};

  int nk = Kd >> 5;
  for (int kt = 0; kt < nk; ++kt) {
    gll16(ap0, asd0); gll16(ap1, asd1);
    gll16(bp0, bsd0); gll16(bp1, bsd1);
    ap0 += 32; ap1 += 32; bp0 += 32; bp1 += 32;
    __syncthreads();
    bf16x8 af[4], bfr[4];
#pragma unroll
    for (int m = 0; m < 4; ++m) {
      int row = wr * 64 + m * 16 + lr;
      af[m] = *(const bf16x8*)&As[row * 32 + ((cg ^ swz(row)) << 3)];
    }
#pragma unroll
    for (int n = 0; n < 4; ++n) {
      int row = wc * 64 + n * 16 + lr;
      bfr[n] = *(const bf16x8*)&Bs[row * 32 + ((cg ^ swz(row)) << 3)];
    }
#pragma unroll
    for (int m = 0; m < 4; ++m)
#pragma unroll
      for (int n = 0; n < 4; ++n)
        acc[m][n] = __builtin_amdgcn_mfma_f32_16x16x32_bf16(af[m], bfr[n], acc[m][n], 0, 0, 0);
    __syncthreads();
  }
  int rq = cg * 4, cq = lr;
#pragma unroll
  for (int m = 0; m < 4; ++m)
#pragma unroll
    for (int n = 0; n < 4; ++n)
#pragma unroll
      for (int r = 0; r < 4; ++r) {
        int row = wr * 64 + m * 16 + rq + r;
        if (row < nrows) {
          int col = n0 + wc * 64 + n * 16 + cq;
          size_t o = (size_t)(rowbase + row) * Nd + col;
          if (BF16OUT) ((ushort*)Out)[o] = f2b(acc[m][n][r]);
          else ((float*)Out)[o] = acc[m][n][r];
        }
      }
}

// y[t] += w0*ye[s0] + w1*ye[s1]   (y already holds shared-expert p)
__global__ void final_kernel(float* __restrict__ y, const ushort* __restrict__ ye,
                             const int* __restrict__ slot_of, const float* __restrict__ tw) {
  int i = blockIdx.x * 256 + threadIdx.x;  // T_TOK*H_DIM/4 threads
  int t = i >> 8;
  int c4 = (i & 255) * 4;
  int s0 = slot_of[t * 2], s1 = slot_of[t * 2 + 1];
  float w0 = tw[t * 2], w1 = tw[t * 2 + 1];
  float4 v = ((float4*)y)[i];
  ushort4 a = *(const ushort4*)(ye + (size_t)s0 * H_DIM + c4);
  ushort4 b = *(const ushort4*)(ye + (size_t)s1 * H_DIM + c4);
  v.x += w0 * b2f(a.x) + w1 * b2f(b.x);
  v.y += w0 * b2f(a.y) + w1 * b2f(b.y);
  v.z += w0 * b2f(a.z) + w1 * b2f(b.z);
  v.w += w0 * b2f(a.w) + w1 * b2f(b.w);
  ((float4*)y)[i] = v;
}

// ---------------- host ----------------
extern "C" void kernel_launch(void* const* d_in, const int* in_sizes, int n_in,
                              void* d_out, int out_size, void* d_ws, size_t ws_size,
                              hipStream_t stream) {
  const float* x       = (const float*)d_in[0];
  const float* g       = (const float*)d_in[1];
  const float* wt      = (const float*)d_in[2];
  const float* wg      = (const float*)d_in[3];
  const float* w_gate  = (const float*)d_in[4];
  const float* w_up    = (const float*)d_in[5];
  const float* w_down  = (const float*)d_in[6];
  const float* sw_gate = (const float*)d_in[7];
  const float* sw_up   = (const float*)d_in[8];
  const float* sw_down = (const float*)d_in[9];
  float* y = (float*)d_out;

  char* p = (char*)d_ws;
  auto alloc = [&](size_t bytes) -> char* {
    char* r = p;
    p += (bytes + 255) & ~(size_t)255;
    return r;
  };
  ushort* xb    = (ushort*)alloc((size_t)T_TOK * H_DIM * 2);
  ushort* wg_t  = (ushort*)alloc((size_t)E_NUM * M_DIM * H_DIM * 2);  // (E, M, H)
  ushort* wu_t  = (ushort*)alloc((size_t)E_NUM * M_DIM * H_DIM * 2);
  ushort* wd_t  = (ushort*)alloc((size_t)E_NUM * H_DIM * M_DIM * 2);  // (E, H, M)
  ushort* swg_t = (ushort*)alloc((size_t)SM_DIM * H_DIM * 2);         // (SM, H)
  ushort* swu_t = (ushort*)alloc((size_t)SM_DIM * H_DIM * 2);
  ushort* swd_t = (ushort*)alloc((size_t)H_DIM * SM_DIM * 2);         // (H, SM)
  float* lg     = (float*)alloc(4 * E_NUM * 4);
  int* tidx     = (int*)alloc(NASSIGN * 4);
  float* tw     = (float*)alloc(NASSIGN * 4);
  int* bcount   = (int*)alloc(NBLK_PLACE * E_NUM * 4);
  int* boffs    = (int*)alloc(NBLK_PLACE * E_NUM * 4);
  int* offs     = (int*)alloc((E_NUM + 1) * 4);
  int* ndesc    = (int*)alloc(4);
  int* perm     = (int*)alloc(NASSIGN * 4);
  int* slot_of  = (int*)alloc(NASSIGN * 4);
  TileDesc* desc = (TileDesc*)alloc(MAX_TILES * sizeof(TileDesc));
  ushort* h_e   = (ushort*)alloc((size_t)NSLOT * M_DIM * 2);
  ushort* hsh   = (ushort*)alloc((size_t)T_TOK * SM_DIM * 2);
  ushort* ye    = (ushort*)alloc((size_t)NSLOT * H_DIM * 2);
  (void)ws_size; (void)in_sizes; (void)n_in; (void)out_size;

  // conversions
  cvt_x_kernel<<<T_TOK * H_DIM / 4 / 256, 256, 0, stream>>>(x, xb);
  dim3 tb(32, 8);
  tcvt_kernel<<<dim3(M_DIM / 32, H_DIM / 32, E_NUM), tb, 0, stream>>>(w_gate, wg_t, H_DIM, M_DIM);
  tcvt_kernel<<<dim3(M_DIM / 32, H_DIM / 32, E_NUM), tb, 0, stream>>>(w_up, wu_t, H_DIM, M_DIM);
  tcvt_kernel<<<dim3(H_DIM / 32, M_DIM / 32, E_NUM), tb, 0, stream>>>(w_down, wd_t, M_DIM, H_DIM);
  tcvt_kernel<<<dim3(SM_DIM / 32, H_DIM / 32, 1), tb, 0, stream>>>(sw_gate, swg_t, H_DIM, SM_DIM);
  tcvt_kernel<<<dim3(SM_DIM / 32, H_DIM / 32, 1), tb, 0, stream>>>(sw_up, swu_t, H_DIM, SM_DIM);
  tcvt_kernel<<<dim3(H_DIM / 32, SM_DIM / 32, 1), tb, 0, stream>>>(sw_down, swd_t, SM_DIM, H_DIM);

  // routing
  lg_kernel<<<1, 32, 0, stream>>>(g, wg, lg);
  router_kernel<<<T_TOK, 64, 0, stream>>>(x, wt, lg, tidx, tw);
  hist_kernel<<<NBLK_PLACE, 256, 0, stream>>>(tidx, bcount);
  scan2_kernel<<<1, 64, 0, stream>>>(bcount, boffs, offs, desc, ndesc);
  place2_kernel<<<NBLK_PLACE, 256, 0, stream>>>(tidx, boffs, perm, slot_of);

  // shared expert: hsh = leaky(x@swg)*(x@swu); y = hsh@swd
  gemm_dual_kernel<<<dim3(T_TOK / 128, SM_DIM / 64), 256, 0, stream>>>(
      xb, swg_t, swu_t, hsh, H_DIM, SM_DIM, nullptr, nullptr, nullptr);
  gemm_single_kernel<0><<<dim3(T_TOK / 128, H_DIM / 128), 256, 0, stream>>>(
      hsh, swd_t, (void*)y, SM_DIM, H_DIM, nullptr, nullptr);

  // routed experts: h_e = leaky(Xg@wg)*(Xg@wu); ye = h_e@wd
  gemm_dual_kernel<<<dim3(MAX_TILES, M_DIM / 64), 256, 0, stream>>>(
      xb, wg_t, wu_t, h_e, H_DIM, M_DIM, perm, desc, ndesc);
  gemm_single_kernel<1><<<dim3(MAX_TILES, H_DIM / 128), 256, 0, stream>>>(
      h_e, wd_t, (void*)ye, M_DIM, H_DIM, desc, ndesc);

  // combine
  final_kernel<<<T_TOK * H_DIM / 4 / 256, 256, 0, stream>>>(y, ye, slot_of, tw);
}

// Round 3
// 241.497 us; speedup vs baseline: 1.8864x; 1.0929x over previous
//
#include <hip/hip_runtime.h>
#include <stdint.h>

// Problem constants (B=4, S=2048, H=1024, E=8, M=512, K=2, SM=1024, G=64)
#define T_TOK 8192
#define H_DIM 1024
#define M_DIM 512
#define SM_DIM 1024
#define E_NUM 8
#define S_SEQ 2048
#define G_DIM 64
#define NASSIGN 16384                      // T_TOK * 2
#define NSLOT (NASSIGN + E_NUM * 128)      // compact slots + per-expert tile padding
#define MAX_TILES (NASSIGN / 128 + E_NUM)  // 136
#define NBLK_PLACE (NASSIGN / 256)         // 64

typedef float f32x4 __attribute__((ext_vector_type(4)));
typedef short bf16x8 __attribute__((ext_vector_type(8)));

struct TileDesc { int base; int expert; int nrows; };

#define WAITCNT_VM4 asm volatile("s_waitcnt vmcnt(4)" ::: "memory")
#define WAITCNT_VM0 asm volatile("s_waitcnt vmcnt(0)" ::: "memory")
#define WAITCNT_LGKM0 asm volatile("s_waitcnt lgkmcnt(0)" ::: "memory")

static __device__ __forceinline__ ushort f2b(float f) {
  union { float f; uint32_t u; } a; a.f = f;
  uint32_t r = a.u + 0x7fffu + ((a.u >> 16) & 1u);  // RNE
  return (ushort)(r >> 16);
}
static __device__ __forceinline__ float b2f(ushort u) {
  union { uint32_t u; float f; } a; a.u = ((uint32_t)u) << 16;
  return a.f;
}
static __device__ __forceinline__ int imin(int a, int b) { return a < b ? a : b; }

// async global->LDS, 16B per lane; LDS dest = wave-uniform base + lane*16
static __device__ __forceinline__ void gll16(const void* g, void* l) {
  __builtin_amdgcn_global_load_lds(
      (const __attribute__((address_space(1))) void*)g,
      (__attribute__((address_space(3))) void*)l, 16, 0, 0);
}
// bank-conflict swizzle for [*][32]-ushort LDS tiles (16B chunks, 4/row)
static __device__ __forceinline__ int swz(int row) { return (row >> 1) & 3; }
// XCD-chunked bijective remap (nwg divisible by 8)
static __device__ __forceinline__ int xcd_remap(int wg, int nwg) {
  return (wg & 7) * (nwg >> 3) + (wg >> 3);
}

// ---------------- conversion kernels ----------------
__global__ void cvt_x_kernel(const float* __restrict__ x, ushort* __restrict__ xb) {
  int i = blockIdx.x * 256 + threadIdx.x;  // T_TOK*H_DIM/4 threads
  const float4 v = ((const float4*)x)[i];
  ushort4 o;
  o.x = f2b(v.x); o.y = f2b(v.y); o.z = f2b(v.z); o.w = f2b(v.w);
  ((ushort4*)xb)[i] = o;
}

// src: batch of (R x C) f32 row-major -> dst: (C x R) bf16 row-major (transpose+convert)
__global__ void tcvt_kernel(const float* __restrict__ src, ushort* __restrict__ dst, int R, int C) {
  __shared__ float tile[32][33];
  size_t bo = (size_t)blockIdx.z * R * C;
  src += bo; dst += bo;
  int c0 = blockIdx.x * 32, r0 = blockIdx.y * 32;
#pragma unroll
  for (int i = 0; i < 4; ++i)
    tile[threadIdx.y + i * 8][threadIdx.x] =
        src[(size_t)(r0 + threadIdx.y + i * 8) * C + c0 + threadIdx.x];
  __syncthreads();
#pragma unroll
  for (int i = 0; i < 4; ++i)
    dst[(size_t)(c0 + threadIdx.y + i * 8) * R + r0 + threadIdx.x] =
        f2b(tile[threadIdx.x][threadIdx.y + i * 8]);
}

// ---------------- routing ----------------
__global__ void lg_kernel(const float* __restrict__ g, const float* __restrict__ wg,
                          float* __restrict__ lg) {
  int tid = threadIdx.x;
  if (tid < 4 * E_NUM) {
    int b = tid >> 3, e = tid & 7;
    float s = 0.f;
    for (int i = 0; i < G_DIM; ++i) s += g[b * G_DIM + i] * wg[e * G_DIM + i];
    lg[tid] = s;
  }
}

// one wave per token: 8 f32 logits, top-2, normalized softmax weights
__global__ __launch_bounds__(64) void router_kernel(
    const float* __restrict__ x, const float* __restrict__ wt, const float* __restrict__ lg,
    int* __restrict__ tidx, float* __restrict__ tw) {
  int t = blockIdx.x;
  int lane = threadIdx.x;
  const float* xr = x + (size_t)t * H_DIM;
  float a[E_NUM];
#pragma unroll
  for (int e = 0; e < E_NUM; ++e) a[e] = 0.f;
  for (int i = lane; i < H_DIM; i += 64) {
    float xv = xr[i];
#pragma unroll
    for (int e = 0; e < E_NUM; ++e) a[e] += xv * wt[e * H_DIM + i];
  }
#pragma unroll
  for (int e = 0; e < E_NUM; ++e)
    for (int off = 32; off; off >>= 1) a[e] += __shfl_xor(a[e], off, 64);
  if (lane == 0) {
    int b = t / S_SEQ;
    float l[E_NUM];
#pragma unroll
    for (int e = 0; e < E_NUM; ++e) l[e] = 0.5f * (a[e] + lg[b * E_NUM + e]);
    int i1 = 0; float b1 = l[0];
#pragma unroll
    for (int e = 1; e < E_NUM; ++e) if (l[e] > b1) { b1 = l[e]; i1 = e; }
    int i2 = -1; float b2 = -1e30f;
#pragma unroll
    for (int e = 0; e < E_NUM; ++e) if (e != i1 && l[e] > b2) { b2 = l[e]; i2 = e; }
    float e2 = expf(b2 - b1);            // e1 = 1
    float inv = 1.f / (1.f + e2);
    tidx[t * 2] = i1; tidx[t * 2 + 1] = i2;
    tw[t * 2] = inv;  tw[t * 2 + 1] = e2 * inv;
  }
}

// per-256-chunk expert histogram
__global__ __launch_bounds__(256) void hist_kernel(const int* __restrict__ tidx,
                                                   int* __restrict__ bcount) {
  __shared__ int h[E_NUM];
  int tid = threadIdx.x;
  if (tid < E_NUM) h[tid] = 0;
  __syncthreads();
  atomicAdd(&h[tidx[blockIdx.x * 256 + tid]], 1);
  __syncthreads();
  if (tid < E_NUM) bcount[blockIdx.x * E_NUM + tid] = h[tid];
}

// one block: totals, expert offsets, tile descriptors, per-chunk global offsets
__global__ __launch_bounds__(64) void scan2_kernel(
    const int* __restrict__ bcount, int* __restrict__ boffs, int* __restrict__ offs,
    TileDesc* __restrict__ desc, int* __restrict__ ndesc) {
  __shared__ int cnt[E_NUM];
  __shared__ int off_s[E_NUM];
  int lane = threadIdx.x;
  if (lane < E_NUM) {
    int s = 0;
    for (int b = 0; b < NBLK_PLACE; ++b) s += bcount[b * E_NUM + lane];
    cnt[lane] = s;
  }
  __syncthreads();
  if (lane == 0) {
    int o = 0, nd = 0;
    for (int e = 0; e < E_NUM; ++e) {
      off_s[e] = o;
      offs[e] = o;
      int n = cnt[e];
      for (int tb = 0; tb < n; tb += 128) {
        desc[nd].base = o + tb; desc[nd].expert = e;
        desc[nd].nrows = imin(n - tb, 128);
        ++nd;
      }
      o += n;
    }
    offs[E_NUM] = o;
    *ndesc = nd;
  }
  __syncthreads();
  if (lane < E_NUM) {
    int run = off_s[lane];
    for (int b = 0; b < NBLK_PLACE; ++b) {
      boffs[b * E_NUM + lane] = run;
      run += bcount[b * E_NUM + lane];
    }
  }
}

// stable parallel compaction: ballot rank within wave + LDS wave-count scan
__global__ __launch_bounds__(256) void place2_kernel(
    const int* __restrict__ tidx, const int* __restrict__ boffs,
    int* __restrict__ perm, int* __restrict__ slot_of) {
  __shared__ int wcnt[4][E_NUM];
  int tid = threadIdx.x, wv = tid >> 6, lane = tid & 63;
  int i = blockIdx.x * 256 + tid;
  int e = tidx[i];
  unsigned long long lower = (lane == 63) ? 0x7fffffffffffffffull : ((1ull << lane) - 1ull);
  int rank = 0;
#pragma unroll
  for (int ee = 0; ee < E_NUM; ++ee) {
    unsigned long long m = __ballot(e == ee);
    if (e == ee) rank = __popcll(m & lower);
    if (lane == 0) wcnt[wv][ee] = __popcll(m);
  }
  __syncthreads();
  int off = boffs[blockIdx.x * E_NUM + e];
  for (int w = 0; w < wv; ++w) off += wcnt[w][e];
  int pos = off + rank;
  perm[pos] = i >> 1;
  slot_of[i] = pos;
}

// ---------------- GEMM kernels: 2-phase prefetch pipeline, dbuf LDS ----------------
// Dual GEMM: out = leaky(A@B0t^T) * (A@B1t^T), bf16 out.  BM=128, BN=64, BK=32.
__global__ __launch_bounds__(256) void gemm_dual_kernel(
    const ushort* __restrict__ A, const ushort* __restrict__ B0t, const ushort* __restrict__ B1t,
    ushort* __restrict__ Hout, int Kd, int Nd, int ncols,
    const int* __restrict__ perm, const TileDesc* __restrict__ desc, const int* __restrict__ ndesc) {
  __shared__ ushort As[2][128 * 32];
  __shared__ ushort B0s[2][64 * 32];
  __shared__ ushort B1s[2][64 * 32];

  int id = xcd_remap(blockIdx.x, gridDim.x);
  int mt = id / ncols, n0 = (id % ncols) * 64;

  int rowbase, nrows;
  const ushort *b0g, *b1g;
  if (desc) {
    if (mt >= *ndesc) return;
    TileDesc d = desc[mt];
    rowbase = d.base; nrows = d.nrows;
    size_t wo = (size_t)d.expert * Nd * Kd;
    b0g = B0t + wo; b1g = B1t + wo;
  } else {
    rowbase = mt * 128; nrows = 128; b0g = B0t; b1g = B1t;
  }
  int tid = threadIdx.x;
  int wv = tid >> 6, lane = tid & 63;

  // staging: wave wv issues A chunks {wv, wv+4}, B0 chunk wv, B1 chunk wv (1KB each)
  int l4 = lane >> 2, c = lane & 3;
  int a0 = wv * 16 + l4, a1 = a0 + 64;   // A tile rows
  int ga0 = desc ? perm[rowbase + imin(a0, nrows - 1)] : (rowbase + a0);
  int ga1 = desc ? perm[rowbase + imin(a1, nrows - 1)] : (rowbase + a1);
  const ushort* ap0 = A + (size_t)ga0 * Kd + ((c ^ swz(a0)) << 3);
  const ushort* ap1 = A + (size_t)ga1 * Kd + ((c ^ swz(a1)) << 3);
  int br = wv * 16 + l4;                 // B tile row (0..63)
  const ushort* bp0 = b0g + (size_t)(n0 + br) * Kd + ((c ^ swz(br)) << 3);
  const ushort* bp1 = b1g + (size_t)(n0 + br) * Kd + ((c ^ swz(br)) << 3);

  int wr = wv >> 1, wc = wv & 1;
  int lr = lane & 15, cg = lane >> 4;

  f32x4 acc0[4][2], acc1[4][2];
#pragma unroll
  for (int m = 0; m < 4; ++m)
#pragma unroll
    for (int n = 0; n < 2; ++n) { acc0[m][n] = (f32x4){0.f,0.f,0.f,0.f}; acc1[m][n] = (f32x4){0.f,0.f,0.f,0.f}; }

  int nk = Kd >> 5;
  // prologue: stage tile 0 into buf 0
  gll16(ap0, &As[0][wv * 512]); gll16(ap1, &As[0][(wv + 4) * 512]);
  gll16(bp0, &B0s[0][wv * 512]); gll16(bp1, &B1s[0][wv * 512]);
  ap0 += 32; ap1 += 32; bp0 += 32; bp1 += 32;

  for (int kt = 0; kt < nk; ++kt) {
    int cur = kt & 1, nxt = cur ^ 1;
    if (kt + 1 < nk) {  // issue next-tile loads (stay in flight across barrier)
      gll16(ap0, &As[nxt][wv * 512]); gll16(ap1, &As[nxt][(wv + 4) * 512]);
      gll16(bp0, &B0s[nxt][wv * 512]); gll16(bp1, &B1s[nxt][wv * 512]);
      ap0 += 32; ap1 += 32; bp0 += 32; bp1 += 32;
      WAITCNT_VM4;      // tile kt landed; 4 newer still flying
    } else {
      WAITCNT_VM0;
    }
    __builtin_amdgcn_s_barrier();   // buf[cur] ready for all waves
    bf16x8 af[4], bq0[2], bq1[2];
#pragma unroll
    for (int m = 0; m < 4; ++m) {
      int row = wr * 64 + m * 16 + lr;
      af[m] = *(const bf16x8*)&As[cur][row * 32 + ((cg ^ swz(row)) << 3)];
    }
#pragma unroll
    for (int n = 0; n < 2; ++n) {
      int row = wc * 32 + n * 16 + lr;
      bq0[n] = *(const bf16x8*)&B0s[cur][row * 32 + ((cg ^ swz(row)) << 3)];
      bq1[n] = *(const bf16x8*)&B1s[cur][row * 32 + ((cg ^ swz(row)) << 3)];
    }
    WAITCNT_LGKM0;                  // reads complete before crossing barrier
    __builtin_amdgcn_s_barrier();   // safe for next iter's STAGE to overwrite
#pragma unroll
    for (int m = 0; m < 4; ++m)
#pragma unroll
      for (int n = 0; n < 2; ++n) {
        acc0[m][n] = __builtin_amdgcn_mfma_f32_16x16x32_bf16(af[m], bq0[n], acc0[m][n], 0, 0, 0);
        acc1[m][n] = __builtin_amdgcn_mfma_f32_16x16x32_bf16(af[m], bq1[n], acc1[m][n], 0, 0, 0);
      }
  }
  // epilogue: h = leaky(g)*u  (C/D layout: col=lane&15, row=(lane>>4)*4+reg)
  int rq = cg * 4, cq = lr;
#pragma unroll
  for (int m = 0; m < 4; ++m)
#pragma unroll
    for (int n = 0; n < 2; ++n)
#pragma unroll
      for (int r = 0; r < 4; ++r) {
        int row = wr * 64 + m * 16 + rq + r;
        if (row < nrows) {
          float gv = acc0[m][n][r], uv = acc1[m][n][r];
          float hv = (gv >= 0.f ? gv : 0.01f * gv) * uv;
          int col = n0 + wc * 32 + n * 16 + cq;
          Hout[(size_t)(rowbase + row) * Nd + col] = f2b(hv);
        }
      }
}

// Single GEMM: out = A@Bt^T.  BM=128, BN=128, BK=32. BF16OUT: 0 -> f32, 1 -> bf16.
template <int BF16OUT>
__global__ __launch_bounds__(256) void gemm_single_kernel(
    const ushort* __restrict__ A, const ushort* __restrict__ Bt, void* __restrict__ Out,
    int Kd, int Nd, int ncols, const TileDesc* __restrict__ desc, const int* __restrict__ ndesc) {
  __shared__ ushort As[2][128 * 32];
  __shared__ ushort Bs[2][128 * 32];

  int id = xcd_remap(blockIdx.x, gridDim.x);
  int mt = id / ncols, n0 = (id % ncols) * 128;

  int rowbase, nrows;
  const ushort* bg;
  if (desc) {
    if (mt >= *ndesc) return;
    TileDesc d = desc[mt];
    rowbase = d.base; nrows = d.nrows;
    bg = Bt + (size_t)d.expert * Nd * Kd;
  } else {
    rowbase = mt * 128; nrows = 128; bg = Bt;
  }
  int tid = threadIdx.x;
  int wv = tid >> 6, lane = tid & 63;

  int l4 = lane >> 2, c = lane & 3;
  int a0 = wv * 16 + l4, a1 = a0 + 64;
  const ushort* ap0 = A + (size_t)(rowbase + a0) * Kd + ((c ^ swz(a0)) << 3);
  const ushort* ap1 = A + (size_t)(rowbase + a1) * Kd + ((c ^ swz(a1)) << 3);
  const ushort* bp0 = bg + (size_t)(n0 + a0) * Kd + ((c ^ swz(a0)) << 3);
  const ushort* bp1 = bg + (size_t)(n0 + a1) * Kd + ((c ^ swz(a1)) << 3);

  int wr = wv >> 1, wc = wv & 1;
  int lr = lane & 15, cg = lane >> 4;

  f32x4 acc[4][4];
#pragma unroll
  for (int m = 0; m < 4; ++m)
#pragma unroll
    for (int n = 0; n < 4; ++n) acc[m][n] = (f32x4){0.f,0.f,0.f,0.f};

  int nk = Kd >> 5;
  gll16(ap0, &As[0][wv * 512]); gll16(ap1, &As[0][(wv + 4) * 512]);
  gll16(bp0, &Bs[0][wv * 512]); gll16(bp1, &Bs[0][(wv + 4) * 512]);
  ap0 += 32; ap1 += 32; bp0 += 32; bp1 += 32;

  for (int kt = 0; kt < nk; ++kt) {
    int cur = kt & 1, nxt = cur ^ 1;
    if (kt + 1 < nk) {
      gll16(ap0, &As[nxt][wv * 512]); gll16(ap1, &As[nxt][(wv + 4) * 512]);
      gll16(bp0, &Bs[nxt][wv * 512]); gll16(bp1, &Bs[nxt][(wv + 4) * 512]);
      ap0 += 32; ap1 += 32; bp0 += 32; bp1 += 32;
      WAITCNT_VM4;
    } else {
      WAITCNT_VM0;
    }
    __builtin_amdgcn_s_barrier();
    bf16x8 af[4], bfr[4];
#pragma unroll
    for (int m = 0; m < 4; ++m) {
      int row = wr * 64 + m * 16 + lr;
      af[m] = *(const bf16x8*)&As[cur][row * 32 + ((cg ^ swz(row)) << 3)];
    }
#pragma unroll
    for (int n = 0; n < 4; ++n) {
      int row = wc * 64 + n * 16 + lr;
      bfr[n] = *(const bf16x8*)&Bs[cur][row * 32 + ((cg ^ swz(row)) << 3)];
    }
    WAITCNT_LGKM0;
    __builtin_amdgcn_s_barrier();
#pragma unroll
    for (int m = 0; m < 4; ++m)
#pragma unroll
      for (int n = 0; n < 4; ++n)
        acc[m][n] = __builtin_amdgcn_mfma_f32_16x16x32_bf16(af[m], bfr[n], acc[m][n], 0, 0, 0);
  }
  int rq = cg * 4, cq = lr;
#pragma unroll
  for (int m = 0; m < 4; ++m)
#pragma unroll
    for (int n = 0; n < 4; ++n)
#pragma unroll
      for (int r = 0; r < 4; ++r) {
        int row = wr * 64 + m * 16 + rq + r;
        if (row < nrows) {
          int col = n0 + wc * 64 + n * 16 + cq;
          size_t o = (size_t)(rowbase + row) * Nd + col;
          if (BF16OUT) ((ushort*)Out)[o] = f2b(acc[m][n][r]);
          else ((float*)Out)[o] = acc[m][n][r];
        }
      }
}

// y[t] += w0*ye[s0] + w1*ye[s1]   (y already holds shared-expert p)
__global__ void final_kernel(float* __restrict__ y, const ushort* __restrict__ ye,
                             const int* __restrict__ slot_of, const float* __restrict__ tw) {
  int i = blockIdx.x * 256 + threadIdx.x;  // T_TOK*H_DIM/4 threads
  int t = i >> 8;
  int c4 = (i & 255) * 4;
  int s0 = slot_of[t * 2], s1 = slot_of[t * 2 + 1];
  float w0 = tw[t * 2], w1 = tw[t * 2 + 1];
  float4 v = ((float4*)y)[i];
  ushort4 a = *(const ushort4*)(ye + (size_t)s0 * H_DIM + c4);
  ushort4 b = *(const ushort4*)(ye + (size_t)s1 * H_DIM + c4);
  v.x += w0 * b2f(a.x) + w1 * b2f(b.x);
  v.y += w0 * b2f(a.y) + w1 * b2f(b.y);
  v.z += w0 * b2f(a.z) + w1 * b2f(b.z);
  v.w += w0 * b2f(a.w) + w1 * b2f(b.w);
  ((float4*)y)[i] = v;
}

// ---------------- host ----------------
extern "C" void kernel_launch(void* const* d_in, const int* in_sizes, int n_in,
                              void* d_out, int out_size, void* d_ws, size_t ws_size,
                              hipStream_t stream) {
  const float* x       = (const float*)d_in[0];
  const float* g       = (const float*)d_in[1];
  const float* wt      = (const float*)d_in[2];
  const float* wg      = (const float*)d_in[3];
  const float* w_gate  = (const float*)d_in[4];
  const float* w_up    = (const float*)d_in[5];
  const float* w_down  = (const float*)d_in[6];
  const float* sw_gate = (const float*)d_in[7];
  const float* sw_up   = (const float*)d_in[8];
  const float* sw_down = (const float*)d_in[9];
  float* y = (float*)d_out;

  char* p = (char*)d_ws;
  auto alloc = [&](size_t bytes) -> char* {
    char* r = p;
    p += (bytes + 255) & ~(size_t)255;
    return r;
  };
  ushort* xb    = (ushort*)alloc((size_t)T_TOK * H_DIM * 2);
  ushort* wg_t  = (ushort*)alloc((size_t)E_NUM * M_DIM * H_DIM * 2);  // (E, M, H)
  ushort* wu_t  = (ushort*)alloc((size_t)E_NUM * M_DIM * H_DIM * 2);
  ushort* wd_t  = (ushort*)alloc((size_t)E_NUM * H_DIM * M_DIM * 2);  // (E, H, M)
  ushort* swg_t = (ushort*)alloc((size_t)SM_DIM * H_DIM * 2);         // (SM, H)
  ushort* swu_t = (ushort*)alloc((size_t)SM_DIM * H_DIM * 2);
  ushort* swd_t = (ushort*)alloc((size_t)H_DIM * SM_DIM * 2);         // (H, SM)
  float* lg     = (float*)alloc(4 * E_NUM * 4);
  int* tidx     = (int*)alloc(NASSIGN * 4);
  float* tw     = (float*)alloc(NASSIGN * 4);
  int* bcount   = (int*)alloc(NBLK_PLACE * E_NUM * 4);
  int* boffs    = (int*)alloc(NBLK_PLACE * E_NUM * 4);
  int* offs     = (int*)alloc((E_NUM + 1) * 4);
  int* ndesc    = (int*)alloc(4);
  int* perm     = (int*)alloc(NASSIGN * 4);
  int* slot_of  = (int*)alloc(NASSIGN * 4);
  TileDesc* desc = (TileDesc*)alloc(MAX_TILES * sizeof(TileDesc));
  ushort* h_e   = (ushort*)alloc((size_t)NSLOT * M_DIM * 2);
  ushort* hsh   = (ushort*)alloc((size_t)T_TOK * SM_DIM * 2);
  ushort* ye    = (ushort*)alloc((size_t)NSLOT * H_DIM * 2);
  (void)ws_size; (void)in_sizes; (void)n_in; (void)out_size;

  // conversions
  cvt_x_kernel<<<T_TOK * H_DIM / 4 / 256, 256, 0, stream>>>(x, xb);
  dim3 tb(32, 8);
  tcvt_kernel<<<dim3(M_DIM / 32, H_DIM / 32, E_NUM), tb, 0, stream>>>(w_gate, wg_t, H_DIM, M_DIM);
  tcvt_kernel<<<dim3(M_DIM / 32, H_DIM / 32, E_NUM), tb, 0, stream>>>(w_up, wu_t, H_DIM, M_DIM);
  tcvt_kernel<<<dim3(H_DIM / 32, M_DIM / 32, E_NUM), tb, 0, stream>>>(w_down, wd_t, M_DIM, H_DIM);
  tcvt_kernel<<<dim3(SM_DIM / 32, H_DIM / 32, 1), tb, 0, stream>>>(sw_gate, swg_t, H_DIM, SM_DIM);
  tcvt_kernel<<<dim3(SM_DIM / 32, H_DIM / 32, 1), tb, 0, stream>>>(sw_up, swu_t, H_DIM, SM_DIM);
  tcvt_kernel<<<dim3(H_DIM / 32, SM_DIM / 32, 1), tb, 0, stream>>>(sw_down, swd_t, SM_DIM, H_DIM);

  // routing
  lg_kernel<<<1, 32, 0, stream>>>(g, wg, lg);
  router_kernel<<<T_TOK, 64, 0, stream>>>(x, wt, lg, tidx, tw);
  hist_kernel<<<NBLK_PLACE, 256, 0, stream>>>(tidx, bcount);
  scan2_kernel<<<1, 64, 0, stream>>>(bcount, boffs, offs, desc, ndesc);
  place2_kernel<<<NBLK_PLACE, 256, 0, stream>>>(tidx, boffs, perm, slot_of);

  // shared expert: hsh = leaky(x@swg)*(x@swu); y = hsh@swd
  gemm_dual_kernel<<<(T_TOK / 128) * (SM_DIM / 64), 256, 0, stream>>>(
      xb, swg_t, swu_t, hsh, H_DIM, SM_DIM, SM_DIM / 64, nullptr, nullptr, nullptr);
  gemm_single_kernel<0><<<(T_TOK / 128) * (H_DIM / 128), 256, 0, stream>>>(
      hsh, swd_t, (void*)y, SM_DIM, H_DIM, H_DIM / 128, nullptr, nullptr);

  // routed experts: h_e = leaky(Xg@wg)*(Xg@wu); ye = h_e@wd
  gemm_dual_kernel<<<MAX_TILES * (M_DIM / 64), 256, 0, stream>>>(
      xb, wg_t, wu_t, h_e, H_DIM, M_DIM, M_DIM / 64, perm, desc, ndesc);
  gemm_single_kernel<1><<<MAX_TILES * (H_DIM / 128), 256, 0, stream>>>(
      h_e, wd_t, (void*)ye, M_DIM, H_DIM, H_DIM / 128, desc, ndesc);

  // combine
  final_kernel<<<T_TOK * H_DIM / 4 / 256, 256, 0, stream>>>(y, ye, slot_of, tw);
}

// Round 4
// 233.254 us; speedup vs baseline: 1.9531x; 1.0353x over previous
//
#include <hip/hip_runtime.h>
#include <stdint.h>

// Problem constants (B=4, S=2048, H=1024, E=8, M=512, K=2, SM=1024, G=64)
#define T_TOK 8192
#define H_DIM 1024
#define M_DIM 512
#define SM_DIM 1024
#define E_NUM 8
#define S_SEQ 2048
#define G_DIM 64
#define NASSIGN 16384                      // T_TOK * 2
#define NSLOT (NASSIGN + E_NUM * 256)      // compact slots + per-expert 256-tile padding
#define MAX_TILES (NASSIGN / 256 + E_NUM)  // 72
#define NBLK_PLACE (NASSIGN / 256)         // 64

typedef float f32x4 __attribute__((ext_vector_type(4)));
typedef short bf16x8 __attribute__((ext_vector_type(8)));

struct TileDesc { int base; int expert; int nrows; };

#define WAITCNT_VM4 asm volatile("s_waitcnt vmcnt(4)" ::: "memory")
#define WAITCNT_VM3 asm volatile("s_waitcnt vmcnt(3)" ::: "memory")
#define WAITCNT_VM0 asm volatile("s_waitcnt vmcnt(0)" ::: "memory")
#define WAITCNT_LGKM0 asm volatile("s_waitcnt lgkmcnt(0)" ::: "memory")

static __device__ __forceinline__ ushort f2b(float f) {
  union { float f; uint32_t u; } a; a.f = f;
  uint32_t r = a.u + 0x7fffu + ((a.u >> 16) & 1u);  // RNE
  return (ushort)(r >> 16);
}
static __device__ __forceinline__ float b2f(ushort u) {
  union { uint32_t u; float f; } a; a.u = ((uint32_t)u) << 16;
  return a.f;
}
static __device__ __forceinline__ int imin(int a, int b) { return a < b ? a : b; }

// async global->LDS, 16B per lane; LDS dest = wave-uniform base + lane*16
static __device__ __forceinline__ void gll16(const void* g, void* l) {
  __builtin_amdgcn_global_load_lds(
      (const __attribute__((address_space(1))) void*)g,
      (__attribute__((address_space(3))) void*)l, 16, 0, 0);
}
// bank-conflict swizzle for [*][32]-ushort LDS tiles (16B chunks, 4/row)
static __device__ __forceinline__ int swz(int row) { return (row >> 1) & 3; }
// XCD-chunked bijective remap (nwg divisible by 8)
static __device__ __forceinline__ int xcd_remap(int wg, int nwg) {
  return (wg & 7) * (nwg >> 3) + (wg >> 3);
}

// ---------------- conversion kernels ----------------
__global__ void cvt_x_kernel(const float* __restrict__ x, ushort* __restrict__ xb) {
  int i = blockIdx.x * 256 + threadIdx.x;  // T_TOK*H_DIM/4 threads
  const float4 v = ((const float4*)x)[i];
  ushort4 o;
  o.x = f2b(v.x); o.y = f2b(v.y); o.z = f2b(v.z); o.w = f2b(v.w);
  ((ushort4*)xb)[i] = o;
}

// src: batch of (R x C) f32 row-major -> dst: (C x R) bf16 row-major (transpose+convert)
__global__ void tcvt_kernel(const float* __restrict__ src, ushort* __restrict__ dst, int R, int C) {
  __shared__ float tile[32][33];
  size_t bo = (size_t)blockIdx.z * R * C;
  src += bo; dst += bo;
  int c0 = blockIdx.x * 32, r0 = blockIdx.y * 32;
#pragma unroll
  for (int i = 0; i < 4; ++i)
    tile[threadIdx.y + i * 8][threadIdx.x] =
        src[(size_t)(r0 + threadIdx.y + i * 8) * C + c0 + threadIdx.x];
  __syncthreads();
#pragma unroll
  for (int i = 0; i < 4; ++i)
    dst[(size_t)(c0 + threadIdx.y + i * 8) * R + r0 + threadIdx.x] =
        f2b(tile[threadIdx.x][threadIdx.y + i * 8]);
}

// ---------------- routing ----------------
__global__ void lg_kernel(const float* __restrict__ g, const float* __restrict__ wg,
                          float* __restrict__ lg) {
  int tid = threadIdx.x;
  if (tid < 4 * E_NUM) {
    int b = tid >> 3, e = tid & 7;
    float s = 0.f;
    for (int i = 0; i < G_DIM; ++i) s += g[b * G_DIM + i] * wg[e * G_DIM + i];
    lg[tid] = s;
  }
}

// one wave per token: 8 f32 logits, top-2, normalized softmax weights
__global__ __launch_bounds__(64) void router_kernel(
    const float* __restrict__ x, const float* __restrict__ wt, const float* __restrict__ lg,
    int* __restrict__ tidx, float* __restrict__ tw) {
  int t = blockIdx.x;
  int lane = threadIdx.x;
  const float* xr = x + (size_t)t * H_DIM;
  float a[E_NUM];
#pragma unroll
  for (int e = 0; e < E_NUM; ++e) a[e] = 0.f;
  for (int i = lane; i < H_DIM; i += 64) {
    float xv = xr[i];
#pragma unroll
    for (int e = 0; e < E_NUM; ++e) a[e] += xv * wt[e * H_DIM + i];
  }
#pragma unroll
  for (int e = 0; e < E_NUM; ++e)
    for (int off = 32; off; off >>= 1) a[e] += __shfl_xor(a[e], off, 64);
  if (lane == 0) {
    int b = t / S_SEQ;
    float l[E_NUM];
#pragma unroll
    for (int e = 0; e < E_NUM; ++e) l[e] = 0.5f * (a[e] + lg[b * E_NUM + e]);
    int i1 = 0; float b1 = l[0];
#pragma unroll
    for (int e = 1; e < E_NUM; ++e) if (l[e] > b1) { b1 = l[e]; i1 = e; }
    int i2 = -1; float b2 = -1e30f;
#pragma unroll
    for (int e = 0; e < E_NUM; ++e) if (e != i1 && l[e] > b2) { b2 = l[e]; i2 = e; }
    float e2 = expf(b2 - b1);            // e1 = 1
    float inv = 1.f / (1.f + e2);
    tidx[t * 2] = i1; tidx[t * 2 + 1] = i2;
    tw[t * 2] = inv;  tw[t * 2 + 1] = e2 * inv;
  }
}

// per-256-chunk expert histogram
__global__ __launch_bounds__(256) void hist_kernel(const int* __restrict__ tidx,
                                                   int* __restrict__ bcount) {
  __shared__ int h[E_NUM];
  int tid = threadIdx.x;
  if (tid < E_NUM) h[tid] = 0;
  __syncthreads();
  atomicAdd(&h[tidx[blockIdx.x * 256 + tid]], 1);
  __syncthreads();
  if (tid < E_NUM) bcount[blockIdx.x * E_NUM + tid] = h[tid];
}

// one block: totals, expert offsets, tile descriptors (256-row), per-chunk offsets
__global__ __launch_bounds__(64) void scan2_kernel(
    const int* __restrict__ bcount, int* __restrict__ boffs, int* __restrict__ offs,
    TileDesc* __restrict__ desc, int* __restrict__ ndesc) {
  __shared__ int cnt[E_NUM];
  __shared__ int off_s[E_NUM];
  int lane = threadIdx.x;
  if (lane < E_NUM) {
    int s = 0;
    for (int b = 0; b < NBLK_PLACE; ++b) s += bcount[b * E_NUM + lane];
    cnt[lane] = s;
  }
  __syncthreads();
  if (lane == 0) {
    int o = 0, nd = 0;
    for (int e = 0; e < E_NUM; ++e) {
      off_s[e] = o;
      offs[e] = o;
      int n = cnt[e];
      for (int tb = 0; tb < n; tb += 256) {
        desc[nd].base = o + tb; desc[nd].expert = e;
        desc[nd].nrows = imin(n - tb, 256);
        ++nd;
      }
      o += n;
    }
    offs[E_NUM] = o;
    *ndesc = nd;
  }
  __syncthreads();
  if (lane < E_NUM) {
    int run = off_s[lane];
    for (int b = 0; b < NBLK_PLACE; ++b) {
      boffs[b * E_NUM + lane] = run;
      run += bcount[b * E_NUM + lane];
    }
  }
}

// stable parallel compaction: ballot rank within wave + LDS wave-count scan
__global__ __launch_bounds__(256) void place2_kernel(
    const int* __restrict__ tidx, const int* __restrict__ boffs,
    int* __restrict__ perm, int* __restrict__ slot_of) {
  __shared__ int wcnt[4][E_NUM];
  int tid = threadIdx.x, wv = tid >> 6, lane = tid & 63;
  int i = blockIdx.x * 256 + tid;
  int e = tidx[i];
  unsigned long long lower = (lane == 63) ? 0x7fffffffffffffffull : ((1ull << lane) - 1ull);
  int rank = 0;
#pragma unroll
  for (int ee = 0; ee < E_NUM; ++ee) {
    unsigned long long m = __ballot(e == ee);
    if (e == ee) rank = __popcll(m & lower);
    if (lane == 0) wcnt[wv][ee] = __popcll(m);
  }
  __syncthreads();
  int off = boffs[blockIdx.x * E_NUM + e];
  for (int w = 0; w < wv; ++w) off += wcnt[w][e];
  int pos = off + rank;
  perm[pos] = i >> 1;
  slot_of[i] = pos;
}

// ---------------- GEMM core: BM=256, 512 thr, 3-buffer deep pipeline ----------------
// DUAL=1: BN=256 over interleaved virtual Bcat (16 gate cols | 16 up cols), epilogue
//         writes h = leaky(g)*u, bf16, NdOut cols.  DUAL=0: BN=128 plain GEMM.
template <int DUAL>
static __device__ __forceinline__ void gemm_core(
    const ushort* __restrict__ A, const ushort* __restrict__ B0,
    const ushort* __restrict__ B1, void* __restrict__ Out, int outf32,
    int Kd, int NdOut, int rowbase, int nrows, int n0,
    const int* __restrict__ perm, ushort* Asb, ushort* Bsb) {
  constexpr int BN = DUAL ? 256 : 128;
  constexpr int BSTRIDE = BN * 32;  // elems per B buffer
  int tid = threadIdx.x, wv = tid >> 6, lane = tid & 63;
  int sr = tid >> 2, sc = tid & 3;  // staging row (0-127), 16B chunk
  int r1 = sr + 128;

  // A staging pointers (rows sr, sr+128 of the 256-row tile)
  int ga0 = perm ? perm[rowbase + imin(sr, nrows - 1)] : (rowbase + sr);
  int ga1 = perm ? perm[rowbase + imin(r1, nrows - 1)] : (rowbase + r1);
  const ushort* ap0 = A + (size_t)ga0 * Kd + ((sc ^ swz(sr)) << 3);
  const ushort* ap1 = A + (size_t)ga1 * Kd + ((sc ^ swz(r1)) << 3);
  // B staging pointers
  const ushort* bp0;
  const ushort* bp1 = nullptr;
  if (DUAL) {
    int rb0 = n0 + sr, rb1 = n0 + r1;  // virtual Bcat rows
    const ushort* s0 = ((rb0 >> 4) & 1) ? B1 : B0;
    const ushort* s1 = ((rb1 >> 4) & 1) ? B1 : B0;
    bp0 = s0 + (size_t)(((rb0 >> 5) << 4) + (rb0 & 15)) * Kd + ((sc ^ swz(sr)) << 3);
    bp1 = s1 + (size_t)(((rb1 >> 5) << 4) + (rb1 & 15)) * Kd + ((sc ^ swz(r1)) << 3);
  } else {
    bp0 = B0 + (size_t)(n0 + sr) * Kd + ((sc ^ swz(sr)) << 3);
  }

  auto stageA = [&](int b) {
    ushort* ad = Asb + b * 8192 + wv * 512;
    gll16(ap0, ad); gll16(ap1, ad + 4096);
    ap0 += 32; ap1 += 32;
  };
  auto stageB = [&](int b) {
    ushort* bd = Bsb + b * BSTRIDE + wv * 512;
    gll16(bp0, bd); bp0 += 32;
    if (DUAL) { gll16(bp1, bd + 4096); bp1 += 32; }
  };

  int wr = wv >> 2, wc = wv & 3;
  int lr = lane & 15, cg = lane >> 4;

  constexpr int NF = DUAL ? 4 : 2;
  f32x4 acc[8][NF];
#pragma unroll
  for (int m = 0; m < 8; ++m)
#pragma unroll
    for (int n = 0; n < NF; ++n) acc[m][n] = (f32x4){0.f, 0.f, 0.f, 0.f};

  int nk = Kd >> 5;
  // prologue: stage tiles 0,1 into bufs 0,1
  stageA(0); stageB(0);
  stageA(1); stageB(1);
  if (DUAL) WAITCNT_VM4; else WAITCNT_VM3;  // tile 0 landed
  __builtin_amdgcn_s_barrier();

  for (int kt = 0; kt < nk; ++kt) {
    int b = kt % 3;
    const ushort* abuf = Asb + b * 8192;
    const ushort* bbuf = Bsb + b * BSTRIDE;
    bool pf = (kt + 2 < nk);
    int b2 = (kt + 2) % 3;

    if (DUAL) {
      bf16x8 af[8];
#pragma unroll
      for (int m = 0; m < 8; ++m) {
        int row = wr * 128 + m * 16 + lr;
        af[m] = *(const bf16x8*)(abuf + row * 32 + ((cg ^ swz(row)) << 3));
      }
      bf16x8 bq[2];
#pragma unroll
      for (int n = 0; n < 2; ++n) {
        int row = wc * 64 + n * 16 + lr;
        bq[n] = *(const bf16x8*)(bbuf + row * 32 + ((cg ^ swz(row)) << 3));
      }
      if (pf) stageA(b2);
      __builtin_amdgcn_s_setprio(1);
#pragma unroll
      for (int m = 0; m < 8; ++m) {
        acc[m][0] = __builtin_amdgcn_mfma_f32_16x16x32_bf16(af[m], bq[0], acc[m][0], 0, 0, 0);
        acc[m][1] = __builtin_amdgcn_mfma_f32_16x16x32_bf16(af[m], bq[1], acc[m][1], 0, 0, 0);
      }
      __builtin_amdgcn_s_setprio(0);
      bf16x8 bq2[2];
#pragma unroll
      for (int n = 0; n < 2; ++n) {
        int row = wc * 64 + (n + 2) * 16 + lr;
        bq2[n] = *(const bf16x8*)(bbuf + row * 32 + ((cg ^ swz(row)) << 3));
      }
      if (pf) stageB(b2);
      __builtin_amdgcn_s_setprio(1);
#pragma unroll
      for (int m = 0; m < 8; ++m) {
        acc[m][2] = __builtin_amdgcn_mfma_f32_16x16x32_bf16(af[m], bq2[0], acc[m][2], 0, 0, 0);
        acc[m][3] = __builtin_amdgcn_mfma_f32_16x16x32_bf16(af[m], bq2[1], acc[m][3], 0, 0, 0);
      }
      __builtin_amdgcn_s_setprio(0);
    } else {
      bf16x8 bq[2];
#pragma unroll
      for (int n = 0; n < 2; ++n) {
        int row = wc * 32 + n * 16 + lr;
        bq[n] = *(const bf16x8*)(bbuf + row * 32 + ((cg ^ swz(row)) << 3));
      }
      bf16x8 af[4];
#pragma unroll
      for (int m = 0; m < 4; ++m) {
        int row = wr * 128 + m * 16 + lr;
        af[m] = *(const bf16x8*)(abuf + row * 32 + ((cg ^ swz(row)) << 3));
      }
      if (pf) { stageA(b2); stageB(b2); }
      __builtin_amdgcn_s_setprio(1);
#pragma unroll
      for (int m = 0; m < 4; ++m) {
        acc[m][0] = __builtin_amdgcn_mfma_f32_16x16x32_bf16(af[m], bq[0], acc[m][0], 0, 0, 0);
        acc[m][1] = __builtin_amdgcn_mfma_f32_16x16x32_bf16(af[m], bq[1], acc[m][1], 0, 0, 0);
      }
      __builtin_amdgcn_s_setprio(0);
      bf16x8 af2[4];
#pragma unroll
      for (int m = 0; m < 4; ++m) {
        int row = wr * 128 + (m + 4) * 16 + lr;
        af2[m] = *(const bf16x8*)(abuf + row * 32 + ((cg ^ swz(row)) << 3));
      }
      __builtin_amdgcn_s_setprio(1);
#pragma unroll
      for (int m = 0; m < 4; ++m) {
        acc[m + 4][0] = __builtin_amdgcn_mfma_f32_16x16x32_bf16(af2[m], bq[0], acc[m + 4][0], 0, 0, 0);
        acc[m + 4][1] = __builtin_amdgcn_mfma_f32_16x16x32_bf16(af2[m], bq[1], acc[m + 4][1], 0, 0, 0);
      }
      __builtin_amdgcn_s_setprio(0);
    }
    WAITCNT_LGKM0;                 // all this-iter LDS reads drained
    if (pf) { if (DUAL) WAITCNT_VM4; else WAITCNT_VM3; }
    else WAITCNT_VM0;
    __builtin_amdgcn_s_barrier();  // tile kt+1 landed; buf reuse safe
  }

  // epilogue (C/D layout: col=lane&15, row=(lane>>4)*4+reg)
  int rq = cg * 4, cq = lr;
  if (DUAL) {
#pragma unroll
    for (int m = 0; m < 8; ++m)
#pragma unroll
      for (int p = 0; p < 2; ++p)
#pragma unroll
        for (int r = 0; r < 4; ++r) {
          int row = wr * 128 + m * 16 + rq + r;
          if (row < nrows) {
            float gv = acc[m][2 * p][r], uv = acc[m][2 * p + 1][r];
            float hv = (gv >= 0.f ? gv : 0.01f * gv) * uv;
            int col = (n0 >> 1) + wc * 32 + p * 16 + cq;
            ((ushort*)Out)[(size_t)(rowbase + row) * NdOut + col] = f2b(hv);
          }
        }
  } else {
#pragma unroll
    for (int m = 0; m < 8; ++m)
#pragma unroll
      for (int n = 0; n < 2; ++n)
#pragma unroll
        for (int r = 0; r < 4; ++r) {
          int row = wr * 128 + m * 16 + rq + r;
          if (row < nrows) {
            int col = n0 + wc * 32 + n * 16 + cq;
            size_t o = (size_t)(rowbase + row) * NdOut + col;
            if (outf32) ((float*)Out)[o] = acc[m][n][r];
            else ((ushort*)Out)[o] = f2b(acc[m][n][r]);
          }
        }
  }
}

// merged dual: blocks [0,256) shared-expert, [256,544) routed experts
__global__ __launch_bounds__(512) void gemm_dual_all(
    const ushort* __restrict__ xb, const ushort* __restrict__ swg,
    const ushort* __restrict__ swu, ushort* __restrict__ hsh,
    const ushort* __restrict__ wg, const ushort* __restrict__ wu,
    ushort* __restrict__ h_e, const int* __restrict__ perm,
    const TileDesc* __restrict__ desc, const int* __restrict__ ndesc) {
  __shared__ ushort Asb[3 * 8192];
  __shared__ ushort Bsb[3 * 8192];
  int id = xcd_remap(blockIdx.x, gridDim.x);
  if (id < 256) {
    int mt = id >> 3, n0 = (id & 7) * 256;
    gemm_core<1>(xb, swg, swu, hsh, 0, H_DIM, SM_DIM, mt * 256, 256, n0, nullptr, Asb, Bsb);
  } else {
    int rid = id - 256;
    int mt = rid >> 2, n0 = (rid & 3) * 256;
    if (mt >= *ndesc) return;
    TileDesc d = desc[mt];
    size_t wo = (size_t)d.expert * M_DIM * H_DIM;
    gemm_core<1>(xb, wg + wo, wu + wo, h_e, 0, H_DIM, M_DIM, d.base, d.nrows, n0, perm, Asb, Bsb);
  }
}

// merged down: blocks [0,256) shared (f32 -> y), [256,832) routed (bf16 -> ye)
__global__ __launch_bounds__(512) void gemm_down_all(
    const ushort* __restrict__ hsh, const ushort* __restrict__ swd, float* __restrict__ y,
    const ushort* __restrict__ h_e, const ushort* __restrict__ wd, ushort* __restrict__ ye,
    const TileDesc* __restrict__ desc, const int* __restrict__ ndesc) {
  __shared__ ushort Asb[3 * 8192];
  __shared__ ushort Bsb[3 * 4096];
  int id = xcd_remap(blockIdx.x, gridDim.x);
  if (id < 256) {
    int mt = id >> 3, n0 = (id & 7) * 128;
    gemm_core<0>(hsh, swd, nullptr, (void*)y, 1, SM_DIM, H_DIM, mt * 256, 256, n0, nullptr, Asb, Bsb);
  } else {
    int rid = id - 256;
    int mt = rid >> 3, n0 = (rid & 7) * 128;
    if (mt >= *ndesc) return;
    TileDesc d = desc[mt];
    gemm_core<0>(h_e, wd + (size_t)d.expert * H_DIM * M_DIM, nullptr, (void*)ye, 0,
                 M_DIM, H_DIM, d.base, d.nrows, n0, nullptr, Asb, Bsb);
  }
}

// y[t] += w0*ye[s0] + w1*ye[s1]   (y already holds shared-expert p)
__global__ void final_kernel(float* __restrict__ y, const ushort* __restrict__ ye,
                             const int* __restrict__ slot_of, const float* __restrict__ tw) {
  int i = blockIdx.x * 256 + threadIdx.x;  // T_TOK*H_DIM/4 threads
  int t = i >> 8;
  int c4 = (i & 255) * 4;
  int s0 = slot_of[t * 2], s1 = slot_of[t * 2 + 1];
  float w0 = tw[t * 2], w1 = tw[t * 2 + 1];
  float4 v = ((float4*)y)[i];
  ushort4 a = *(const ushort4*)(ye + (size_t)s0 * H_DIM + c4);
  ushort4 b = *(const ushort4*)(ye + (size_t)s1 * H_DIM + c4);
  v.x += w0 * b2f(a.x) + w1 * b2f(b.x);
  v.y += w0 * b2f(a.y) + w1 * b2f(b.y);
  v.z += w0 * b2f(a.z) + w1 * b2f(b.z);
  v.w += w0 * b2f(a.w) + w1 * b2f(b.w);
  ((float4*)y)[i] = v;
}

// ---------------- host ----------------
extern "C" void kernel_launch(void* const* d_in, const int* in_sizes, int n_in,
                              void* d_out, int out_size, void* d_ws, size_t ws_size,
                              hipStream_t stream) {
  const float* x       = (const float*)d_in[0];
  const float* g       = (const float*)d_in[1];
  const float* wt      = (const float*)d_in[2];
  const float* wg      = (const float*)d_in[3];
  const float* w_gate  = (const float*)d_in[4];
  const float* w_up    = (const float*)d_in[5];
  const float* w_down  = (const float*)d_in[6];
  const float* sw_gate = (const float*)d_in[7];
  const float* sw_up   = (const float*)d_in[8];
  const float* sw_down = (const float*)d_in[9];
  float* y = (float*)d_out;

  char* p = (char*)d_ws;
  auto alloc = [&](size_t bytes) -> char* {
    char* r = p;
    p += (bytes + 255) & ~(size_t)255;
    return r;
  };
  ushort* xb    = (ushort*)alloc((size_t)T_TOK * H_DIM * 2);
  ushort* wg_t  = (ushort*)alloc((size_t)E_NUM * M_DIM * H_DIM * 2);  // (E, M, H)
  ushort* wu_t  = (ushort*)alloc((size_t)E_NUM * M_DIM * H_DIM * 2);
  ushort* wd_t  = (ushort*)alloc((size_t)E_NUM * H_DIM * M_DIM * 2);  // (E, H, M)
  ushort* swg_t = (ushort*)alloc((size_t)SM_DIM * H_DIM * 2);         // (SM, H)
  ushort* swu_t = (ushort*)alloc((size_t)SM_DIM * H_DIM * 2);
  ushort* swd_t = (ushort*)alloc((size_t)H_DIM * SM_DIM * 2);         // (H, SM)
  float* lg     = (float*)alloc(4 * E_NUM * 4);
  int* tidx     = (int*)alloc(NASSIGN * 4);
  float* tw     = (float*)alloc(NASSIGN * 4);
  int* bcount   = (int*)alloc(NBLK_PLACE * E_NUM * 4);
  int* boffs    = (int*)alloc(NBLK_PLACE * E_NUM * 4);
  int* offs     = (int*)alloc((E_NUM + 1) * 4);
  int* ndesc    = (int*)alloc(4);
  int* perm     = (int*)alloc(NASSIGN * 4);
  int* slot_of  = (int*)alloc(NASSIGN * 4);
  TileDesc* desc = (TileDesc*)alloc(MAX_TILES * sizeof(TileDesc));
  ushort* h_e   = (ushort*)alloc((size_t)NSLOT * M_DIM * 2);
  ushort* hsh   = (ushort*)alloc((size_t)T_TOK * SM_DIM * 2);
  ushort* ye    = (ushort*)alloc((size_t)NSLOT * H_DIM * 2);
  (void)ws_size; (void)in_sizes; (void)n_in; (void)out_size;

  // conversions
  cvt_x_kernel<<<T_TOK * H_DIM / 4 / 256, 256, 0, stream>>>(x, xb);
  dim3 tb(32, 8);
  tcvt_kernel<<<dim3(M_DIM / 32, H_DIM / 32, E_NUM), tb, 0, stream>>>(w_gate, wg_t, H_DIM, M_DIM);
  tcvt_kernel<<<dim3(M_DIM / 32, H_DIM / 32, E_NUM), tb, 0, stream>>>(w_up, wu_t, H_DIM, M_DIM);
  tcvt_kernel<<<dim3(H_DIM / 32, M_DIM / 32, E_NUM), tb, 0, stream>>>(w_down, wd_t, M_DIM, H_DIM);
  tcvt_kernel<<<dim3(SM_DIM / 32, H_DIM / 32, 1), tb, 0, stream>>>(sw_gate, swg_t, H_DIM, SM_DIM);
  tcvt_kernel<<<dim3(SM_DIM / 32, H_DIM / 32, 1), tb, 0, stream>>>(sw_up, swu_t, H_DIM, SM_DIM);
  tcvt_kernel<<<dim3(H_DIM / 32, SM_DIM / 32, 1), tb, 0, stream>>>(sw_down, swd_t, SM_DIM, H_DIM);

  // routing
  lg_kernel<<<1, 32, 0, stream>>>(g, wg, lg);
  router_kernel<<<T_TOK, 64, 0, stream>>>(x, wt, lg, tidx, tw);
  hist_kernel<<<NBLK_PLACE, 256, 0, stream>>>(tidx, bcount);
  scan2_kernel<<<1, 64, 0, stream>>>(bcount, boffs, offs, desc, ndesc);
  place2_kernel<<<NBLK_PLACE, 256, 0, stream>>>(tidx, boffs, perm, slot_of);

  // fused gate/up duals (shared + routed in one launch)
  gemm_dual_all<<<256 + MAX_TILES * 4, 512, 0, stream>>>(
      xb, swg_t, swu_t, hsh, wg_t, wu_t, h_e, perm, desc, ndesc);
  // down projections (shared -> y f32, routed -> ye bf16, one launch)
  gemm_down_all<<<256 + MAX_TILES * 8, 512, 0, stream>>>(
      hsh, swd_t, y, h_e, wd_t, ye, desc, ndesc);

  // combine
  final_kernel<<<T_TOK * H_DIM / 4 / 256, 256, 0, stream>>>(y, ye, slot_of, tw);
}

// Round 5
// 222.195 us; speedup vs baseline: 2.0503x; 1.0498x over previous
//
#include <hip/hip_runtime.h>
#include <stdint.h>

// Problem constants (B=4, S=2048, H=1024, E=8, M=512, K=2, SM=1024, G=64)
#define T_TOK 8192
#define H_DIM 1024
#define M_DIM 512
#define SM_DIM 1024
#define E_NUM 8
#define S_SEQ 2048
#define G_DIM 64
#define NASSIGN 16384                      // T_TOK * 2
#define NSLOT (NASSIGN + E_NUM * 256)      // compact slots + per-expert 256-tile padding
#define MAX_TILES (NASSIGN / 256 + E_NUM)  // 72
#define NBLK_PLACE (NASSIGN / 256)         // 64

typedef float f32x4 __attribute__((ext_vector_type(4)));
typedef short bf16x8 __attribute__((ext_vector_type(8)));

struct TileDesc { int base; int expert; int nrows; };

#define WAITCNT_VM6 asm volatile("s_waitcnt vmcnt(6)" ::: "memory")
#define WAITCNT_VM4 asm volatile("s_waitcnt vmcnt(4)" ::: "memory")
#define WAITCNT_VM2 asm volatile("s_waitcnt vmcnt(2)" ::: "memory")
#define WAITCNT_VM0 asm volatile("s_waitcnt vmcnt(0)" ::: "memory")
#define WAITCNT_LGKM0 asm volatile("s_waitcnt lgkmcnt(0)" ::: "memory")

static __device__ __forceinline__ ushort f2b(float f) {
  union { float f; uint32_t u; } a; a.f = f;
  uint32_t r = a.u + 0x7fffu + ((a.u >> 16) & 1u);  // RNE
  return (ushort)(r >> 16);
}
static __device__ __forceinline__ float b2f(ushort u) {
  union { uint32_t u; float f; } a; a.u = ((uint32_t)u) << 16;
  return a.f;
}
static __device__ __forceinline__ int imin(int a, int b) { return a < b ? a : b; }

// async global->LDS, 16B per lane; LDS dest = wave-uniform base + lane*16
static __device__ __forceinline__ void gll16(const void* g, void* l) {
  __builtin_amdgcn_global_load_lds(
      (const __attribute__((address_space(1))) void*)g,
      (__attribute__((address_space(3))) void*)l, 16, 0, 0);
}
// XCD-chunked bijective remap (nwg divisible by 8)
static __device__ __forceinline__ int xcd_remap(int wg, int nwg) {
  return (wg & 7) * (nwg >> 3) + (wg >> 3);
}

// ---------------- conversion kernels ----------------
__global__ void cvt_x_kernel(const float* __restrict__ x, ushort* __restrict__ xb) {
  int i = blockIdx.x * 256 + threadIdx.x;  // T_TOK*H_DIM/4 threads
  const float4 v = ((const float4*)x)[i];
  ushort4 o;
  o.x = f2b(v.x); o.y = f2b(v.y); o.z = f2b(v.z); o.w = f2b(v.w);
  ((ushort4*)xb)[i] = o;
}

// src: batch of (R x C) f32 row-major -> dst: (C x R) bf16 row-major (transpose+convert)
__global__ void tcvt_kernel(const float* __restrict__ src, ushort* __restrict__ dst, int R, int C) {
  __shared__ float tile[32][33];
  size_t bo = (size_t)blockIdx.z * R * C;
  src += bo; dst += bo;
  int c0 = blockIdx.x * 32, r0 = blockIdx.y * 32;
#pragma unroll
  for (int i = 0; i < 4; ++i)
    tile[threadIdx.y + i * 8][threadIdx.x] =
        src[(size_t)(r0 + threadIdx.y + i * 8) * C + c0 + threadIdx.x];
  __syncthreads();
#pragma unroll
  for (int i = 0; i < 4; ++i)
    dst[(size_t)(c0 + threadIdx.y + i * 8) * R + r0 + threadIdx.x] =
        f2b(tile[threadIdx.x][threadIdx.y + i * 8]);
}

// ---------------- routing ----------------
__global__ void lg_kernel(const float* __restrict__ g, const float* __restrict__ wg,
                          float* __restrict__ lg) {
  int tid = threadIdx.x;
  if (tid < 4 * E_NUM) {
    int b = tid >> 3, e = tid & 7;
    float s = 0.f;
    for (int i = 0; i < G_DIM; ++i) s += g[b * G_DIM + i] * wg[e * G_DIM + i];
    lg[tid] = s;
  }
}

// one wave per token: 8 f32 logits, top-2, normalized softmax weights
__global__ __launch_bounds__(64) void router_kernel(
    const float* __restrict__ x, const float* __restrict__ wt, const float* __restrict__ lg,
    int* __restrict__ tidx, float* __restrict__ tw) {
  int t = blockIdx.x;
  int lane = threadIdx.x;
  const float* xr = x + (size_t)t * H_DIM;
  float a[E_NUM];
#pragma unroll
  for (int e = 0; e < E_NUM; ++e) a[e] = 0.f;
  for (int i = lane; i < H_DIM; i += 64) {
    float xv = xr[i];
#pragma unroll
    for (int e = 0; e < E_NUM; ++e) a[e] += xv * wt[e * H_DIM + i];
  }
#pragma unroll
  for (int e = 0; e < E_NUM; ++e)
    for (int off = 32; off; off >>= 1) a[e] += __shfl_xor(a[e], off, 64);
  if (lane == 0) {
    int b = t / S_SEQ;
    float l[E_NUM];
#pragma unroll
    for (int e = 0; e < E_NUM; ++e) l[e] = 0.5f * (a[e] + lg[b * E_NUM + e]);
    int i1 = 0; float b1 = l[0];
#pragma unroll
    for (int e = 1; e < E_NUM; ++e) if (l[e] > b1) { b1 = l[e]; i1 = e; }
    int i2 = -1; float b2 = -1e30f;
#pragma unroll
    for (int e = 0; e < E_NUM; ++e) if (e != i1 && l[e] > b2) { b2 = l[e]; i2 = e; }
    float e2 = expf(b2 - b1);            // e1 = 1
    float inv = 1.f / (1.f + e2);
    tidx[t * 2] = i1; tidx[t * 2 + 1] = i2;
    tw[t * 2] = inv;  tw[t * 2 + 1] = e2 * inv;
  }
}

// per-256-chunk expert histogram
__global__ __launch_bounds__(256) void hist_kernel(const int* __restrict__ tidx,
                                                   int* __restrict__ bcount) {
  __shared__ int h[E_NUM];
  int tid = threadIdx.x;
  if (tid < E_NUM) h[tid] = 0;
  __syncthreads();
  atomicAdd(&h[tidx[blockIdx.x * 256 + tid]], 1);
  __syncthreads();
  if (tid < E_NUM) bcount[blockIdx.x * E_NUM + tid] = h[tid];
}

// one block: totals, expert offsets, tile descriptors (256-row), per-chunk offsets
__global__ __launch_bounds__(64) void scan2_kernel(
    const int* __restrict__ bcount, int* __restrict__ boffs, int* __restrict__ offs,
    TileDesc* __restrict__ desc, int* __restrict__ ndesc) {
  __shared__ int cnt[E_NUM];
  __shared__ int off_s[E_NUM];
  int lane = threadIdx.x;
  if (lane < E_NUM) {
    int s = 0;
    for (int b = 0; b < NBLK_PLACE; ++b) s += bcount[b * E_NUM + lane];
    cnt[lane] = s;
  }
  __syncthreads();
  if (lane == 0) {
    int o = 0, nd = 0;
    for (int e = 0; e < E_NUM; ++e) {
      off_s[e] = o;
      offs[e] = o;
      int n = cnt[e];
      for (int tb = 0; tb < n; tb += 256) {
        desc[nd].base = o + tb; desc[nd].expert = e;
        desc[nd].nrows = imin(n - tb, 256);
        ++nd;
      }
      o += n;
    }
    offs[E_NUM] = o;
    *ndesc = nd;
  }
  __syncthreads();
  if (lane < E_NUM) {
    int run = off_s[lane];
    for (int b = 0; b < NBLK_PLACE; ++b) {
      boffs[b * E_NUM + lane] = run;
      run += bcount[b * E_NUM + lane];
    }
  }
}

// stable parallel compaction: ballot rank within wave + LDS wave-count scan
__global__ __launch_bounds__(256) void place2_kernel(
    const int* __restrict__ tidx, const int* __restrict__ boffs,
    int* __restrict__ perm, int* __restrict__ slot_of) {
  __shared__ int wcnt[4][E_NUM];
  int tid = threadIdx.x, wv = tid >> 6, lane = tid & 63;
  int i = blockIdx.x * 256 + tid;
  int e = tidx[i];
  unsigned long long lower = (lane == 63) ? 0x7fffffffffffffffull : ((1ull << lane) - 1ull);
  int rank = 0;
#pragma unroll
  for (int ee = 0; ee < E_NUM; ++ee) {
    unsigned long long m = __ballot(e == ee);
    if (e == ee) rank = __popcll(m & lower);
    if (lane == 0) wcnt[wv][ee] = __popcll(m);
  }
  __syncthreads();
  int off = boffs[blockIdx.x * E_NUM + e];
  for (int w = 0; w < wv; ++w) off += wcnt[w][e];
  int pos = off + rank;
  perm[pos] = i >> 1;
  slot_of[i] = pos;
}

// ======== GEMM core: BM=256, BN=256(virt), BK=64, 8 waves, 4-phase K-tile ========
// LDS (ushort units): A piece: d*16384 + qm*8192 + idx*64 + ((chunk^(idx&7))*8)
//                     B piece: 32768 + d*16384 + qn*8192 + idx*64 + (...)
// A idx = wr*64+m*16+lr  <->  row = wr*128 + qm*64 + m*16 + lr
// B idx = wc*32+n*16+lr  <->  vrow = wc*64 + qn*32 + n*16 + lr  (+n0)
template <int DUAL>
static __device__ __forceinline__ void gemm_core8(
    const ushort* __restrict__ A, const ushort* __restrict__ B0,
    const ushort* __restrict__ B1, void* __restrict__ Out, int outf32,
    int Kd, int NdOut, int rowbase, int nrows, int n0,
    const int* __restrict__ perm, ushort* __restrict__ LDS) {
  int tid = threadIdx.x, wv = tid >> 6, lane = tid & 63;
  int wr = wv >> 2, wc = wv & 3;
  int lr = lane & 15, cg = lane >> 4;
  int sid = lane >> 3, dch = lane & 7;

  // staging source pointers [piece][round]
  const ushort* apA[2][2];
  const ushort* apB[2][2];
#pragma unroll
  for (int qm = 0; qm < 2; ++qm)
#pragma unroll
    for (int k = 0; k < 2; ++k) {
      int idx = k * 64 + wv * 8 + sid;
      int gch = dch ^ (idx & 7);
      int grow = (idx >> 6) * 128 + qm * 64 + (idx & 63);
      grow = imin(grow, nrows - 1);
      int arow = perm ? perm[rowbase + grow] : rowbase + grow;
      apA[qm][k] = A + (size_t)arow * Kd + gch * 8;
    }
#pragma unroll
  for (int qn = 0; qn < 2; ++qn)
#pragma unroll
    for (int k = 0; k < 2; ++k) {
      int idx = k * 64 + wv * 8 + sid;
      int gch = dch ^ (idx & 7);
      int vrow = n0 + (idx >> 5) * 64 + qn * 32 + (idx & 31);
      const ushort* src; int brow;
      if (DUAL) {
        src = ((vrow >> 4) & 1) ? B1 : B0;
        brow = (vrow >> 5) * 16 + (vrow & 15);
      } else {
        src = B0; brow = vrow;
      }
      apB[qn][k] = src + (size_t)brow * Kd + gch * 8;
    }

  auto stgA = [&](int qm, int k, int nd) {
    gll16(apA[qm][k], LDS + nd * 16384 + qm * 8192 + (k * 512 + wv * 64) * 8);
    apA[qm][k] += 64;
  };
  auto stgB = [&](int qn, int k, int nd) {
    gll16(apB[qn][k], LDS + 32768 + nd * 16384 + qn * 8192 + (k * 512 + wv * 64) * 8);
    apB[qn][k] += 64;
  };
  auto rdA = [&](int d, int qm, int m, int kk) -> bf16x8 {
    int idx = wr * 64 + m * 16 + lr;
    int ch = (kk * 4 + cg) ^ (idx & 7);
    return *(const bf16x8*)(LDS + d * 16384 + qm * 8192 + idx * 64 + ch * 8);
  };
  auto rdB = [&](int d, int qn, int n, int kk) -> bf16x8 {
    int idx = wc * 32 + n * 16 + lr;
    int ch = (kk * 4 + cg) ^ (idx & 7);
    return *(const bf16x8*)(LDS + 32768 + d * 16384 + qn * 8192 + idx * 64 + ch * 8);
  };

  f32x4 acc[2][2][4][2];
#pragma unroll
  for (int qm = 0; qm < 2; ++qm)
#pragma unroll
    for (int qn = 0; qn < 2; ++qn)
#pragma unroll
      for (int m = 0; m < 4; ++m)
#pragma unroll
        for (int n = 0; n < 2; ++n) acc[qm][qn][m][n] = (f32x4){0.f, 0.f, 0.f, 0.f};

  int nk = Kd >> 6;
  // prologue: stage tile 0 into dbuf 0, piece order A0,B0,B1,A1
  stgA(0, 0, 0); stgA(0, 1, 0);
  stgB(0, 0, 0); stgB(0, 1, 0);
  stgB(1, 0, 0); stgB(1, 1, 0);
  stgA(1, 0, 0); stgA(1, 1, 0);
  WAITCNT_VM4;  // A0,B0 landed
  __builtin_amdgcn_s_barrier();

  for (int t = 0; t < nk; ++t) {
    int cur = t & 1, nxt = cur ^ 1;
    bool hn = (t + 1 < nk);
    bf16x8 a0f[4][2], a1f[4][2], b0f[2][2], b1f[2][2];

    // ---- phase 0: read A0,B0; stage A0'; MFMA Q(0,0)
#pragma unroll
    for (int m = 0; m < 4; ++m) { a0f[m][0] = rdA(cur, 0, m, 0); a0f[m][1] = rdA(cur, 0, m, 1); }
#pragma unroll
    for (int n = 0; n < 2; ++n) { b0f[n][0] = rdB(cur, 0, n, 0); b0f[n][1] = rdB(cur, 0, n, 1); }
    if (hn) { stgA(0, 0, nxt); stgA(0, 1, nxt); WAITCNT_VM4; } else { WAITCNT_VM2; }
    WAITCNT_LGKM0;
    __builtin_amdgcn_s_barrier();
    __builtin_amdgcn_s_setprio(1);
#pragma unroll
    for (int m = 0; m < 4; ++m)
#pragma unroll
      for (int n = 0; n < 2; ++n) {
        acc[0][0][m][n] = __builtin_amdgcn_mfma_f32_16x16x32_bf16(a0f[m][0], b0f[n][0], acc[0][0][m][n], 0, 0, 0);
        acc[0][0][m][n] = __builtin_amdgcn_mfma_f32_16x16x32_bf16(a0f[m][1], b0f[n][1], acc[0][0][m][n], 0, 0, 0);
      }
    __builtin_amdgcn_s_setprio(0);

    // ---- phase 1: read B1; stage B0'; MFMA Q(0,1)
#pragma unroll
    for (int n = 0; n < 2; ++n) { b1f[n][0] = rdB(cur, 1, n, 0); b1f[n][1] = rdB(cur, 1, n, 1); }
    if (hn) { stgB(0, 0, nxt); stgB(0, 1, nxt); WAITCNT_VM4; } else { WAITCNT_VM0; }
    WAITCNT_LGKM0;
    __builtin_amdgcn_s_barrier();
    __builtin_amdgcn_s_setprio(1);
#pragma unroll
    for (int m = 0; m < 4; ++m)
#pragma unroll
      for (int n = 0; n < 2; ++n) {
        acc[0][1][m][n] = __builtin_amdgcn_mfma_f32_16x16x32_bf16(a0f[m][0], b1f[n][0], acc[0][1][m][n], 0, 0, 0);
        acc[0][1][m][n] = __builtin_amdgcn_mfma_f32_16x16x32_bf16(a0f[m][1], b1f[n][1], acc[0][1][m][n], 0, 0, 0);
      }
    __builtin_amdgcn_s_setprio(0);

    // ---- phase 2: read A1; stage B1'; MFMA Q(1,0)
#pragma unroll
    for (int m = 0; m < 4; ++m) { a1f[m][0] = rdA(cur, 1, m, 0); a1f[m][1] = rdA(cur, 1, m, 1); }
    if (hn) { stgB(1, 0, nxt); stgB(1, 1, nxt); WAITCNT_VM6; }
    WAITCNT_LGKM0;
    __builtin_amdgcn_s_barrier();
    __builtin_amdgcn_s_setprio(1);
#pragma unroll
    for (int m = 0; m < 4; ++m)
#pragma unroll
      for (int n = 0; n < 2; ++n) {
        acc[1][0][m][n] = __builtin_amdgcn_mfma_f32_16x16x32_bf16(a1f[m][0], b0f[n][0], acc[1][0][m][n], 0, 0, 0);
        acc[1][0][m][n] = __builtin_amdgcn_mfma_f32_16x16x32_bf16(a1f[m][1], b0f[n][1], acc[1][0][m][n], 0, 0, 0);
      }
    __builtin_amdgcn_s_setprio(0);

    // ---- phase 3: stage A1'; MFMA Q(1,1)
    if (hn) { stgA(1, 0, nxt); stgA(1, 1, nxt); WAITCNT_VM4; }
    WAITCNT_LGKM0;
    __builtin_amdgcn_s_barrier();
    __builtin_amdgcn_s_setprio(1);
#pragma unroll
    for (int m = 0; m < 4; ++m)
#pragma unroll
      for (int n = 0; n < 2; ++n) {
        acc[1][1][m][n] = __builtin_amdgcn_mfma_f32_16x16x32_bf16(a1f[m][0], b1f[n][0], acc[1][1][m][n], 0, 0, 0);
        acc[1][1][m][n] = __builtin_amdgcn_mfma_f32_16x16x32_bf16(a1f[m][1], b1f[n][1], acc[1][1][m][n], 0, 0, 0);
      }
    __builtin_amdgcn_s_setprio(0);
  }

  // epilogue (C/D layout: col=lane&15, row=(lane>>4)*4+reg)
#pragma unroll
  for (int qm = 0; qm < 2; ++qm)
#pragma unroll
    for (int qn = 0; qn < 2; ++qn)
#pragma unroll
      for (int m = 0; m < 4; ++m)
#pragma unroll
        for (int r = 0; r < 4; ++r) {
          int row = wr * 128 + qm * 64 + m * 16 + cg * 4 + r;
          if (row < nrows) {
            if (DUAL) {
              float gv = acc[qm][qn][m][0][r], uv = acc[qm][qn][m][1][r];
              float hv = (gv >= 0.f ? gv : 0.01f * gv) * uv;
              int col = ((n0 >> 5) + wc * 2 + qn) * 16 + lr;
              ((ushort*)Out)[(size_t)(rowbase + row) * NdOut + col] = f2b(hv);
            } else {
#pragma unroll
              for (int n = 0; n < 2; ++n) {
                int col = n0 + wc * 64 + qn * 32 + n * 16 + lr;
                size_t o = (size_t)(rowbase + row) * NdOut + col;
                if (outf32) ((float*)Out)[o] = acc[qm][qn][m][n][r];
                else ((ushort*)Out)[o] = f2b(acc[qm][qn][m][n][r]);
              }
            }
          }
        }
}

// merged dual: blocks [0,256) shared-expert, [256,544) routed experts
__global__ __launch_bounds__(512) void gemm_dual_all(
    const ushort* __restrict__ xb, const ushort* __restrict__ swg,
    const ushort* __restrict__ swu, ushort* __restrict__ hsh,
    const ushort* __restrict__ wg, const ushort* __restrict__ wu,
    ushort* __restrict__ h_e, const int* __restrict__ perm,
    const TileDesc* __restrict__ desc, const int* __restrict__ ndesc) {
  __shared__ ushort LDS[65536];  // 128 KB
  int id = xcd_remap(blockIdx.x, gridDim.x);
  if (id < 256) {
    int mt = id >> 3, n0 = (id & 7) * 256;
    gemm_core8<1>(xb, swg, swu, hsh, 0, H_DIM, SM_DIM, mt * 256, 256, n0, nullptr, LDS);
  } else {
    int rid = id - 256;
    int mt = rid >> 2, n0 = (rid & 3) * 256;
    if (mt >= *ndesc) return;
    TileDesc d = desc[mt];
    size_t wo = (size_t)d.expert * M_DIM * H_DIM;
    gemm_core8<1>(xb, wg + wo, wu + wo, h_e, 0, H_DIM, M_DIM, d.base, d.nrows, n0, perm, LDS);
  }
}

// merged down: blocks [0,128) shared (f32 -> y), [128,416) routed (bf16 -> ye)
__global__ __launch_bounds__(512) void gemm_down_all(
    const ushort* __restrict__ hsh, const ushort* __restrict__ swd, float* __restrict__ y,
    const ushort* __restrict__ h_e, const ushort* __restrict__ wd, ushort* __restrict__ ye,
    const TileDesc* __restrict__ desc, const int* __restrict__ ndesc) {
  __shared__ ushort LDS[65536];  // 128 KB
  int id = xcd_remap(blockIdx.x, gridDim.x);
  if (id < 128) {
    int mt = id >> 2, n0 = (id & 3) * 256;
    gemm_core8<0>(hsh, swd, nullptr, (void*)y, 1, SM_DIM, H_DIM, mt * 256, 256, n0, nullptr, LDS);
  } else {
    int rid = id - 128;
    int mt = rid >> 2, n0 = (rid & 3) * 256;
    if (mt >= *ndesc) return;
    TileDesc d = desc[mt];
    gemm_core8<0>(h_e, wd + (size_t)d.expert * H_DIM * M_DIM, nullptr, (void*)ye, 0,
                  M_DIM, H_DIM, d.base, d.nrows, n0, nullptr, LDS);
  }
}

// y[t] += w0*ye[s0] + w1*ye[s1]   (y already holds shared-expert p)
__global__ void final_kernel(float* __restrict__ y, const ushort* __restrict__ ye,
                             const int* __restrict__ slot_of, const float* __restrict__ tw) {
  int i = blockIdx.x * 256 + threadIdx.x;  // T_TOK*H_DIM/4 threads
  int t = i >> 8;
  int c4 = (i & 255) * 4;
  int s0 = slot_of[t * 2], s1 = slot_of[t * 2 + 1];
  float w0 = tw[t * 2], w1 = tw[t * 2 + 1];
  float4 v = ((float4*)y)[i];
  ushort4 a = *(const ushort4*)(ye + (size_t)s0 * H_DIM + c4);
  ushort4 b = *(const ushort4*)(ye + (size_t)s1 * H_DIM + c4);
  v.x += w0 * b2f(a.x) + w1 * b2f(b.x);
  v.y += w0 * b2f(a.y) + w1 * b2f(b.y);
  v.z += w0 * b2f(a.z) + w1 * b2f(b.z);
  v.w += w0 * b2f(a.w) + w1 * b2f(b.w);
  ((float4*)y)[i] = v;
}

// ---------------- host ----------------
extern "C" void kernel_launch(void* const* d_in, const int* in_sizes, int n_in,
                              void* d_out, int out_size, void* d_ws, size_t ws_size,
                              hipStream_t stream) {
  const float* x       = (const float*)d_in[0];
  const float* g       = (const float*)d_in[1];
  const float* wt      = (const float*)d_in[2];
  const float* wg      = (const float*)d_in[3];
  const float* w_gate  = (const float*)d_in[4];
  const float* w_up    = (const float*)d_in[5];
  const float* w_down  = (const float*)d_in[6];
  const float* sw_gate = (const float*)d_in[7];
  const float* sw_up   = (const float*)d_in[8];
  const float* sw_down = (const float*)d_in[9];
  float* y = (float*)d_out;

  char* p = (char*)d_ws;
  auto alloc = [&](size_t bytes) -> char* {
    char* r = p;
    p += (bytes + 255) & ~(size_t)255;
    return r;
  };
  ushort* xb    = (ushort*)alloc((size_t)T_TOK * H_DIM * 2);
  ushort* wg_t  = (ushort*)alloc((size_t)E_NUM * M_DIM * H_DIM * 2);  // (E, M, H)
  ushort* wu_t  = (ushort*)alloc((size_t)E_NUM * M_DIM * H_DIM * 2);
  ushort* wd_t  = (ushort*)alloc((size_t)E_NUM * H_DIM * M_DIM * 2);  // (E, H, M)
  ushort* swg_t = (ushort*)alloc((size_t)SM_DIM * H_DIM * 2);         // (SM, H)
  ushort* swu_t = (ushort*)alloc((size_t)SM_DIM * H_DIM * 2);
  ushort* swd_t = (ushort*)alloc((size_t)H_DIM * SM_DIM * 2);         // (H, SM)
  float* lg     = (float*)alloc(4 * E_NUM * 4);
  int* tidx     = (int*)alloc(NASSIGN * 4);
  float* tw     = (float*)alloc(NASSIGN * 4);
  int* bcount   = (int*)alloc(NBLK_PLACE * E_NUM * 4);
  int* boffs    = (int*)alloc(NBLK_PLACE * E_NUM * 4);
  int* offs     = (int*)alloc((E_NUM + 1) * 4);
  int* ndesc    = (int*)alloc(4);
  int* perm     = (int*)alloc(NASSIGN * 4);
  int* slot_of  = (int*)alloc(NASSIGN * 4);
  TileDesc* desc = (TileDesc*)alloc(MAX_TILES * sizeof(TileDesc));
  ushort* h_e   = (ushort*)alloc((size_t)NSLOT * M_DIM * 2);
  ushort* hsh   = (ushort*)alloc((size_t)T_TOK * SM_DIM * 2);
  ushort* ye    = (ushort*)alloc((size_t)NSLOT * H_DIM * 2);
  (void)ws_size; (void)in_sizes; (void)n_in; (void)out_size;

  // conversions
  cvt_x_kernel<<<T_TOK * H_DIM / 4 / 256, 256, 0, stream>>>(x, xb);
  dim3 tb(32, 8);
  tcvt_kernel<<<dim3(M_DIM / 32, H_DIM / 32, E_NUM), tb, 0, stream>>>(w_gate, wg_t, H_DIM, M_DIM);
  tcvt_kernel<<<dim3(M_DIM / 32, H_DIM / 32, E_NUM), tb, 0, stream>>>(w_up, wu_t, H_DIM, M_DIM);
  tcvt_kernel<<<dim3(H_DIM / 32, M_DIM / 32, E_NUM), tb, 0, stream>>>(w_down, wd_t, M_DIM, H_DIM);
  tcvt_kernel<<<dim3(SM_DIM / 32, H_DIM / 32, 1), tb, 0, stream>>>(sw_gate, swg_t, H_DIM, SM_DIM);
  tcvt_kernel<<<dim3(SM_DIM / 32, H_DIM / 32, 1), tb, 0, stream>>>(sw_up, swu_t, H_DIM, SM_DIM);
  tcvt_kernel<<<dim3(H_DIM / 32, SM_DIM / 32, 1), tb, 0, stream>>>(sw_down, swd_t, SM_DIM, H_DIM);

  // routing
  lg_kernel<<<1, 32, 0, stream>>>(g, wg, lg);
  router_kernel<<<T_TOK, 64, 0, stream>>>(x, wt, lg, tidx, tw);
  hist_kernel<<<NBLK_PLACE, 256, 0, stream>>>(tidx, bcount);
  scan2_kernel<<<1, 64, 0, stream>>>(bcount, boffs, offs, desc, ndesc);
  place2_kernel<<<NBLK_PLACE, 256, 0, stream>>>(tidx, boffs, perm, slot_of);

  // fused gate/up duals (shared + routed in one launch)
  gemm_dual_all<<<256 + MAX_TILES * 4, 512, 0, stream>>>(
      xb, swg_t, swu_t, hsh, wg_t, wu_t, h_e, perm, desc, ndesc);
  // down projections (shared -> y f32, routed -> ye bf16, one launch)
  gemm_down_all<<<128 + MAX_TILES * 4, 512, 0, stream>>>(
      hsh, swd_t, y, h_e, wd_t, ye, desc, ndesc);

  // combine
  final_kernel<<<T_TOK * H_DIM / 4 / 256, 256, 0, stream>>>(y, ye, slot_of, tw);
}